// Round 1
// baseline (1730.244 us; speedup 1.0000x reference)
//
#include <hip/hip_runtime.h>

// ---------------------------------------------------------------------------
// InputMapCTRNN: T=256, B=128, I=64, C=256, H=512, O=128, ALPHA=1, EPS=1e-5
//
// Reassociation: h[t,b,n] = relu( sum_c ctx[t,b,c]*S_c[t,b,n] + S_bias )
//   with S_c[m,n] = sum_i x[m,i] * WbT[n, c*64+i],  WbT[n][c*64+i] = Wmap[n*64+i][c]
// -> one MFMA GEMM M=32768,N=512,K=16448 with fp32 per-c scaling of partials.
// Only the small ctx recurrence is sequential (fp32, Wcc bf16 in registers).
// ---------------------------------------------------------------------------

typedef unsigned int  uint_t;
typedef unsigned short ushort_t;
typedef __attribute__((ext_vector_type(8))) short  short8;
typedef __attribute__((ext_vector_type(4))) float  floatx4;

__device__ __forceinline__ ushort_t f2bf(float f) {
    uint_t u = __float_as_uint(f);
    u = (u + 0x7fffu + ((u >> 16) & 1u)) >> 16;   // RNE
    return (ushort_t)u;
}
__device__ __forceinline__ uint_t pack2(float a, float b) {
    return (uint_t)f2bf(a) | ((uint_t)f2bf(b) << 16);
}
__device__ __forceinline__ float blo(uint_t u) { return __uint_as_float(u << 16); }
__device__ __forceinline__ float bhi(uint_t u) { return __uint_as_float(u & 0xffff0000u); }

// ---------------------------------------------------------------------------
// prep: WbT (transpose+convert Wmap, append bmap), Whh/Who/x -> bf16
// grid: 512 (WbT) + 16 (Whh) + 4 (Who) + 512 (xbf) = 1044 blocks x 256
// ---------------------------------------------------------------------------
__global__ void k_prep(const float* __restrict__ x, const float* __restrict__ Wmap,
                       const float* __restrict__ bmap, const float* __restrict__ Whh,
                       const float* __restrict__ Who,
                       ushort_t* WbT, ushort_t* Whhb, ushort_t* Whob, ushort_t* xbf) {
    __shared__ __align__(16) float tl[32 * 257];
    const int tid = threadIdx.x;
    const int bid = blockIdx.x;
    if (bid < 512) {
        const int n = bid;
        for (int p = 0; p < 2; ++p) {
            if (p) __syncthreads();
#pragma unroll
            for (int k = 0; k < 32; ++k)
                tl[k * 257 + tid] = Wmap[(size_t)(n * 64 + p * 32 + k) * 256 + tid];
            __syncthreads();
#pragma unroll
            for (int k2 = 0; k2 < 32; ++k2) {
                int o = k2 * 256 + tid;
                int il = o & 31, c = o >> 5;
                WbT[(size_t)n * 16448 + c * 64 + p * 32 + il] = f2bf(tl[il * 257 + c]);
            }
        }
        if (tid < 64) WbT[(size_t)n * 16448 + 16384 + tid] = f2bf(bmap[n * 64 + tid]);
    } else if (bid < 528) {
        size_t base = (size_t)(bid - 512) * 16384;
#pragma unroll
        for (int k = 0; k < 64; ++k) { size_t i = base + k * 256 + tid; Whhb[i] = f2bf(Whh[i]); }
    } else if (bid < 532) {
        size_t base = (size_t)(bid - 528) * 16384;
#pragma unroll
        for (int k = 0; k < 64; ++k) { size_t i = base + k * 256 + tid; Whob[i] = f2bf(Who[i]); }
    } else {
        size_t base = (size_t)(bid - 532) * 4096;
#pragma unroll
        for (int k = 0; k < 16; ++k) { size_t i = base + k * 256 + tid; xbf[i] = f2bf(x[i]); }
    }
}

// ---------------------------------------------------------------------------
// Xc[m][j] = bic[j]+bcc[j] + sum_i Wic[j][i]*x[m][i]   (fp32, feeds recurrence)
// grid 512 x 256 ; block handles 64 rows m
// ---------------------------------------------------------------------------
__global__ __launch_bounds__(256, 1) void k_xc(const float* __restrict__ x,
                                               const float* __restrict__ Wic,
                                               const float* __restrict__ bic,
                                               const float* __restrict__ bcc,
                                               float* __restrict__ Xc) {
    __shared__ __align__(16) float xs[64 * 64];
    const int tid = threadIdx.x;
    const int m0 = blockIdx.x * 64;
#pragma unroll
    for (int k = 0; k < 16; ++k) xs[k * 256 + tid] = x[(size_t)m0 * 64 + k * 256 + tid];
    float wv[64];
#pragma unroll
    for (int q = 0; q < 16; ++q) {
        float4 f = *(const float4*)(Wic + tid * 64 + q * 4);
        wv[q * 4] = f.x; wv[q * 4 + 1] = f.y; wv[q * 4 + 2] = f.z; wv[q * 4 + 3] = f.w;
    }
    const float bias = bic[tid] + bcc[tid];
    __syncthreads();
    for (int mr = 0; mr < 64; ++mr) {
        float acc = bias;
#pragma unroll
        for (int q = 0; q < 16; ++q) {
            float4 xv = *(const float4*)(xs + mr * 64 + q * 4);
            acc = fmaf(wv[q * 4], xv.x, acc);
            acc = fmaf(wv[q * 4 + 1], xv.y, acc);
            acc = fmaf(wv[q * 4 + 2], xv.z, acc);
            acc = fmaf(wv[q * 4 + 3], xv.w, acc);
        }
        Xc[(size_t)(m0 + mr) * 256 + tid] = acc;
    }
}

// ---------------------------------------------------------------------------
// Sequential ctx recurrence. One block per batch sample b (128 blocks x 256).
// Wcc held bf16-packed in 128 VGPRs/thread (row tid); ctx fp32 in LDS.
// Writes CTX[t][b][:] (ctx ENTERING step t, fp32) and final ctx to d_out tail.
// ---------------------------------------------------------------------------
__global__ __launch_bounds__(256, 1) void k_rec(const float* __restrict__ Wcc,
                                                const float* __restrict__ Xc,
                                                float* __restrict__ CTX,
                                                float* __restrict__ ctx_out) {
    __shared__ float cur[256];
    const int tid = threadIdx.x;
    const int b = blockIdx.x;
    uint_t wreg[128];
#pragma unroll
    for (int q = 0; q < 64; ++q) {
        float4 f = *(const float4*)(Wcc + tid * 256 + q * 4);
        wreg[2 * q] = pack2(f.x, f.y);
        wreg[2 * q + 1] = pack2(f.z, f.w);
    }
    cur[tid] = 0.f;
    float myc = 0.f;
    __syncthreads();
#pragma unroll 1
    for (int t = 0; t < 256; ++t) {
        const size_t m = (size_t)t * 128 + b;
        CTX[m * 256 + tid] = myc;
        float acc = Xc[m * 256 + tid];
#pragma unroll
        for (int c8 = 0; c8 < 32; ++c8) {
            float4 cA = *(const float4*)(cur + c8 * 8);
            float4 cB = *(const float4*)(cur + c8 * 8 + 4);
            uint_t w0 = wreg[c8 * 4], w1 = wreg[c8 * 4 + 1], w2 = wreg[c8 * 4 + 2], w3 = wreg[c8 * 4 + 3];
            acc = fmaf(blo(w0), cA.x, acc); acc = fmaf(bhi(w0), cA.y, acc);
            acc = fmaf(blo(w1), cA.z, acc); acc = fmaf(bhi(w1), cA.w, acc);
            acc = fmaf(blo(w2), cB.x, acc); acc = fmaf(bhi(w2), cB.y, acc);
            acc = fmaf(blo(w3), cB.z, acc); acc = fmaf(bhi(w3), cB.w, acc);
        }
        myc = fmaxf(acc, 0.f);
        __syncthreads();
        cur[tid] = myc;
        __syncthreads();
    }
    ctx_out[b * 256 + tid] = myc;
}

// ---------------------------------------------------------------------------
// transpose CTX [m][c] f32 -> CTXT [c][m] f32 (for coalesced per-c scale reads)
// grid 2048 x 256: 64x64 tiles
// ---------------------------------------------------------------------------
__global__ void k_tr(const float* __restrict__ CTX, float* __restrict__ CTXT) {
    __shared__ __align__(16) float tl[64 * 65];
    const int tid = threadIdx.x, bid = blockIdx.x;
    const int m0 = (bid >> 2) * 64, c0 = (bid & 3) * 64;
#pragma unroll
    for (int k = 0; k < 16; ++k) {
        int idx = k * 256 + tid;
        int mr = idx >> 6, cc = idx & 63;
        tl[mr * 65 + cc] = CTX[(size_t)(m0 + mr) * 256 + c0 + cc];
    }
    __syncthreads();
#pragma unroll
    for (int k = 0; k < 16; ++k) {
        int idx = k * 256 + tid;
        int cr = idx >> 6, mm = idx & 63;
        CTXT[(size_t)(c0 + cr) * 32768 + m0 + mm] = tl[mm * 65 + cr];
    }
}

// ---------------------------------------------------------------------------
// THE BIG ONE: h = relu( sum_c ctx[m,c]*S_c + S_bias ),  M=32768,N=512,K=16448
// 128x128 tile, 4 waves, 16x16x32 bf16 MFMA. A-frags (x rows) loaded once.
// B streamed global->reg->padded LDS. fp32 scale per 64-K-block.
// grid (256,4) x 256
// ---------------------------------------------------------------------------
__global__ __launch_bounds__(256, 2) void k_big(const ushort_t* __restrict__ xbf,
                                                const ushort_t* __restrict__ WbT,
                                                const float* __restrict__ CTXT,
                                                ushort_t* __restrict__ hbf) {
    __shared__ __align__(16) ushort_t Bt[128 * 72];   // stride 72 shorts = 144 B (pad)
    const int tid = threadIdx.x;
    const int lane = tid & 63, w = tid >> 6;
    const int wm = w & 1, wn = w >> 1;
    const int l15 = lane & 15, quad = lane >> 4;
    const int m0 = blockIdx.x * 128, n0 = blockIdx.y * 128;

    short8 afr[4][2];
#pragma unroll
    for (int mt = 0; mt < 4; ++mt)
#pragma unroll
        for (int ks = 0; ks < 2; ++ks)
            afr[mt][ks] = *(const short8*)(xbf + (size_t)(m0 + wm * 64 + mt * 16 + l15) * 64 + ks * 32 + quad * 8);

    floatx4 acc[4][4];
#pragma unroll
    for (int i = 0; i < 4; ++i)
#pragma unroll
        for (int j = 0; j < 4; ++j) acc[i][j] = (floatx4){0.f, 0.f, 0.f, 0.f};

    const int n_l = tid >> 1, kh = (tid & 1) * 32;
    const ushort_t* gB = WbT + (size_t)(n0 + n_l) * 16448 + kh;
    ushort_t* lB = &Bt[n_l * 72 + kh];

    uint4 rr0 = *(const uint4*)(gB + 0);
    uint4 rr1 = *(const uint4*)(gB + 8);
    uint4 rr2 = *(const uint4*)(gB + 16);
    uint4 rr3 = *(const uint4*)(gB + 24);

    const floatx4 fz = {0.f, 0.f, 0.f, 0.f};
    for (int cb = 0; cb < 257; ++cb) {
        __syncthreads();
        *(uint4*)(lB + 0) = rr0;
        *(uint4*)(lB + 8) = rr1;
        *(uint4*)(lB + 16) = rr2;
        *(uint4*)(lB + 24) = rr3;
        __syncthreads();
        if (cb + 1 < 257) {
            const ushort_t* g = gB + (size_t)(cb + 1) * 64;
            rr0 = *(const uint4*)(g + 0);  rr1 = *(const uint4*)(g + 8);
            rr2 = *(const uint4*)(g + 16); rr3 = *(const uint4*)(g + 24);
        }
        floatx4 sc[4];
        if (cb < 256) {
#pragma unroll
            for (int mt = 0; mt < 4; ++mt)
                sc[mt] = *(const floatx4*)(CTXT + (size_t)cb * 32768 + m0 + wm * 64 + mt * 16 + quad * 4);
        } else {
#pragma unroll
            for (int mt = 0; mt < 4; ++mt) sc[mt] = (floatx4){1.f, 1.f, 1.f, 1.f};
        }
#pragma unroll
        for (int nt = 0; nt < 4; ++nt) {
            const int nr = wn * 64 + nt * 16 + l15;
            short8 b0 = *(const short8*)(&Bt[nr * 72 + quad * 8]);
            short8 b1 = *(const short8*)(&Bt[nr * 72 + 32 + quad * 8]);
#pragma unroll
            for (int mt = 0; mt < 4; ++mt) {
                floatx4 t0 = __builtin_amdgcn_mfma_f32_16x16x32_bf16(afr[mt][0], b0, fz, 0, 0, 0);
                t0 = __builtin_amdgcn_mfma_f32_16x16x32_bf16(afr[mt][1], b1, t0, 0, 0, 0);
                acc[mt][nt] += sc[mt] * t0;
            }
        }
    }
#pragma unroll
    for (int mt = 0; mt < 4; ++mt)
#pragma unroll
        for (int nt = 0; nt < 4; ++nt) {
            const int col = n0 + wn * 64 + nt * 16 + l15;
#pragma unroll
            for (int r = 0; r < 4; ++r) {
                const int row = m0 + wm * 64 + mt * 16 + quad * 4 + r;
                hbf[(size_t)row * 512 + col] = f2bf(fmaxf(acc[mt][nt][r], 0.f));
            }
        }
}

// ---------------------------------------------------------------------------
// Generic bf16 NT GEMM: C[m,n] = sum_k A[m,k]*B[n,k] + bias[n]
// A,B staged global->reg->padded LDS per 64-K step. out bf16 or f32.
// ---------------------------------------------------------------------------
template <bool OUTF32>
__global__ __launch_bounds__(256, 2) void k_gemm_nt(const ushort_t* __restrict__ A,
                                                    const ushort_t* __restrict__ Bm,
                                                    const float* __restrict__ bias,
                                                    ushort_t* __restrict__ outb,
                                                    float* __restrict__ outf,
                                                    int K, int Nst) {
    __shared__ __align__(16) ushort_t At[128 * 72];
    __shared__ __align__(16) ushort_t Bt[128 * 72];
    const int tid = threadIdx.x;
    const int lane = tid & 63, w = tid >> 6;
    const int wm = w & 1, wn = w >> 1;
    const int l15 = lane & 15, quad = lane >> 4;
    const int m0 = blockIdx.x * 128, n0 = blockIdx.y * 128;

    const int r_l = tid >> 1, kh = (tid & 1) * 32;
    const ushort_t* gA = A + (size_t)(m0 + r_l) * K + kh;
    const ushort_t* gB = Bm + (size_t)(n0 + r_l) * K + kh;
    ushort_t* lA = &At[r_l * 72 + kh];
    ushort_t* lB = &Bt[r_l * 72 + kh];

    uint4 ra0 = *(const uint4*)(gA + 0), ra1 = *(const uint4*)(gA + 8);
    uint4 ra2 = *(const uint4*)(gA + 16), ra3 = *(const uint4*)(gA + 24);
    uint4 rb0 = *(const uint4*)(gB + 0), rb1 = *(const uint4*)(gB + 8);
    uint4 rb2 = *(const uint4*)(gB + 16), rb3 = *(const uint4*)(gB + 24);

    floatx4 acc[4][4];
#pragma unroll
    for (int i = 0; i < 4; ++i)
#pragma unroll
        for (int j = 0; j < 4; ++j) acc[i][j] = (floatx4){0.f, 0.f, 0.f, 0.f};

    const int niter = K >> 6;
    for (int kb = 0; kb < niter; ++kb) {
        __syncthreads();
        *(uint4*)(lA + 0) = ra0;  *(uint4*)(lA + 8) = ra1;
        *(uint4*)(lA + 16) = ra2; *(uint4*)(lA + 24) = ra3;
        *(uint4*)(lB + 0) = rb0;  *(uint4*)(lB + 8) = rb1;
        *(uint4*)(lB + 16) = rb2; *(uint4*)(lB + 24) = rb3;
        __syncthreads();
        if (kb + 1 < niter) {
            const ushort_t* ga = gA + (size_t)(kb + 1) * 64;
            const ushort_t* gb = gB + (size_t)(kb + 1) * 64;
            ra0 = *(const uint4*)(ga + 0);  ra1 = *(const uint4*)(ga + 8);
            ra2 = *(const uint4*)(ga + 16); ra3 = *(const uint4*)(ga + 24);
            rb0 = *(const uint4*)(gb + 0);  rb1 = *(const uint4*)(gb + 8);
            rb2 = *(const uint4*)(gb + 16); rb3 = *(const uint4*)(gb + 24);
        }
        short8 av[4][2];
#pragma unroll
        for (int mt = 0; mt < 4; ++mt) {
            const int mr = wm * 64 + mt * 16 + l15;
            av[mt][0] = *(const short8*)(&At[mr * 72 + quad * 8]);
            av[mt][1] = *(const short8*)(&At[mr * 72 + 32 + quad * 8]);
        }
#pragma unroll
        for (int nt = 0; nt < 4; ++nt) {
            const int nr = wn * 64 + nt * 16 + l15;
            short8 b0 = *(const short8*)(&Bt[nr * 72 + quad * 8]);
            short8 b1 = *(const short8*)(&Bt[nr * 72 + 32 + quad * 8]);
#pragma unroll
            for (int mt = 0; mt < 4; ++mt) {
                acc[mt][nt] = __builtin_amdgcn_mfma_f32_16x16x32_bf16(av[mt][0], b0, acc[mt][nt], 0, 0, 0);
                acc[mt][nt] = __builtin_amdgcn_mfma_f32_16x16x32_bf16(av[mt][1], b1, acc[mt][nt], 0, 0, 0);
            }
        }
    }
#pragma unroll
    for (int mt = 0; mt < 4; ++mt)
#pragma unroll
        for (int nt = 0; nt < 4; ++nt) {
            const int col = n0 + wn * 64 + nt * 16 + l15;
            const float bb = bias[col];
#pragma unroll
            for (int r = 0; r < 4; ++r) {
                const int row = m0 + wm * 64 + mt * 16 + quad * 4 + r;
                const float v = acc[mt][nt][r] + bb;
                if (OUTF32) outf[(size_t)row * Nst + col] = v;
                else        outb[(size_t)row * Nst + col] = f2bf(v);
            }
        }
}

// ---------------------------------------------------------------------------
// LayerNorm + residual: z = h + relu( (hn-mu)*rsqrt(var+eps)*g + b ), in-place
// over hbf. One wave per row of 512. grid 8192 x 256.
// ---------------------------------------------------------------------------
__global__ __launch_bounds__(256, 1) void k_ln(const ushort_t* __restrict__ hn,
                                               ushort_t* __restrict__ h,
                                               const float* __restrict__ g,
                                               const float* __restrict__ bb) {
    const int tid = threadIdx.x;
    const int lane = tid & 63;
    const int row = blockIdx.x * 4 + (tid >> 6);
    const uint4 hv = *(const uint4*)(hn + (size_t)row * 512 + lane * 8);
    float f[8];
    f[0] = blo(hv.x); f[1] = bhi(hv.x); f[2] = blo(hv.y); f[3] = bhi(hv.y);
    f[4] = blo(hv.z); f[5] = bhi(hv.z); f[6] = blo(hv.w); f[7] = bhi(hv.w);
    float s = 0.f, s2 = 0.f;
#pragma unroll
    for (int j = 0; j < 8; ++j) { s += f[j]; s2 = fmaf(f[j], f[j], s2); }
#pragma unroll
    for (int o = 32; o >= 1; o >>= 1) { s += __shfl_xor(s, o, 64); s2 += __shfl_xor(s2, o, 64); }
    const float mu = s * (1.f / 512.f);
    const float var = s2 * (1.f / 512.f) - mu * mu;
    const float rs = rsqrtf(var + 1e-5f);
    const uint4 hh = *(const uint4*)(h + (size_t)row * 512 + lane * 8);
    float hf[8];
    hf[0] = blo(hh.x); hf[1] = bhi(hh.x); hf[2] = blo(hh.y); hf[3] = bhi(hh.y);
    hf[4] = blo(hh.z); hf[5] = bhi(hh.z); hf[6] = blo(hh.w); hf[7] = bhi(hh.w);
    float4 g0 = *(const float4*)(g + lane * 8);  float4 g1 = *(const float4*)(g + lane * 8 + 4);
    float4 b0 = *(const float4*)(bb + lane * 8); float4 b1 = *(const float4*)(bb + lane * 8 + 4);
    const float gv[8] = {g0.x, g0.y, g0.z, g0.w, g1.x, g1.y, g1.z, g1.w};
    const float bv[8] = {b0.x, b0.y, b0.z, b0.w, b1.x, b1.y, b1.z, b1.w};
    float z[8];
#pragma unroll
    for (int j = 0; j < 8; ++j)
        z[j] = hf[j] + fmaxf((f[j] - mu) * rs * gv[j] + bv[j], 0.f);
    uint4 o;
    o.x = pack2(z[0], z[1]); o.y = pack2(z[2], z[3]);
    o.z = pack2(z[4], z[5]); o.w = pack2(z[6], z[7]);
    *(uint4*)(h + (size_t)row * 512 + lane * 8) = o;
}

// ---------------------------------------------------------------------------
extern "C" void kernel_launch(void* const* d_in, const int* in_sizes, int n_in,
                              void* d_out, int out_size, void* d_ws, size_t ws_size,
                              hipStream_t stream) {
    const float* x    = (const float*)d_in[0];
    const float* Wcc  = (const float*)d_in[1];
    const float* bcc  = (const float*)d_in[2];
    const float* Wic  = (const float*)d_in[3];
    const float* bic  = (const float*)d_in[4];
    const float* Wmap = (const float*)d_in[5];
    const float* bmap = (const float*)d_in[6];
    const float* Whh  = (const float*)d_in[7];
    const float* bhh  = (const float*)d_in[8];
    const float* ln_g = (const float*)d_in[9];
    const float* ln_b = (const float*)d_in[10];
    const float* Who  = (const float*)d_in[11];
    const float* bho  = (const float*)d_in[12];
    float* out = (float*)d_out;

    char* wsb = (char*)d_ws;
    ushort_t* WbT  = (ushort_t*)(wsb);                    // 16,842,752 B
    ushort_t* Whhb = (ushort_t*)(wsb + 16842752);         //    524,288
    ushort_t* Whob = (ushort_t*)(wsb + 17367040);         //    131,072
    ushort_t* xbf  = (ushort_t*)(wsb + 17498112);         //  4,194,304
    float*    Xc   = (float*)   (wsb + 21692416);         // 33,554,432
    float*    CTX  = (float*)   (wsb + 55246848);         // 33,554,432
    float*    CTXT = (float*)   (wsb + 88801280);         // 33,554,432
    ushort_t* hbf  = (ushort_t*)(wsb + 122355712);        // 33,554,432 (h, then z in-place)
    ushort_t* hnbf = (ushort_t*)(wsb + 155910144);        // 33,554,432  -> total ~189 MB

    k_prep<<<1044, 256, 0, stream>>>(x, Wmap, bmap, Whh, Who, WbT, Whhb, Whob, xbf);
    k_xc<<<512, 256, 0, stream>>>(x, Wic, bic, bcc, Xc);
    k_rec<<<128, 256, 0, stream>>>(Wcc, Xc, CTX, out + 4194304);
    k_tr<<<2048, 256, 0, stream>>>(CTX, CTXT);
    k_big<<<dim3(256, 4), 256, 0, stream>>>(xbf, WbT, CTXT, hbf);
    k_gemm_nt<false><<<dim3(256, 4), 256, 0, stream>>>(hbf, Whhb, bhh, hnbf, nullptr, 512, 512);
    k_ln<<<8192, 256, 0, stream>>>(hnbf, hbf, ln_g, ln_b);
    k_gemm_nt<true><<<dim3(256, 1), 256, 0, stream>>>(hbf, Whob, bho, nullptr, out, 512, 128);
}

// Round 2
// 1128.395 us; speedup vs baseline: 1.5334x; 1.5334x over previous
//
#include <hip/hip_runtime.h>

// ---------------------------------------------------------------------------
// InputMapCTRNN: T=256, B=128, I=64, C=256, H=512, O=128, ALPHA=1, EPS=1e-5
//
// h[t,b,n] = relu( sum_c ctx[t,b,c]*S_c + S_bias ),
//   S_c[m,n] = sum_i x[m,i]*WbT[n, c*64+i]  -> one MFMA GEMM M=32768,N=512,
//   K=16448 with fp32 per-c scaling. Recurrence = batched MFMA (8 blocks).
// ---------------------------------------------------------------------------

typedef unsigned int  uint_t;
typedef unsigned short ushort_t;
typedef __attribute__((ext_vector_type(8))) short  short8;
typedef __attribute__((ext_vector_type(4))) short  short4v;
typedef __attribute__((ext_vector_type(4))) float  floatx4;

__device__ __forceinline__ ushort_t f2bf(float f) {
    uint_t u = __float_as_uint(f);
    u = (u + 0x7fffu + ((u >> 16) & 1u)) >> 16;   // RNE
    return (ushort_t)u;
}
__device__ __forceinline__ uint_t pack2(float a, float b) {
    return (uint_t)f2bf(a) | ((uint_t)f2bf(b) << 16);
}
__device__ __forceinline__ float blo(uint_t u) { return __uint_as_float(u << 16); }
__device__ __forceinline__ float bhi(uint_t u) { return __uint_as_float(u & 0xffff0000u); }

__device__ __forceinline__ void glds16(const void* g, void* l) {
    __builtin_amdgcn_global_load_lds(
        (const __attribute__((address_space(1))) unsigned int*)g,
        (__attribute__((address_space(3))) unsigned int*)l, 16, 0, 0);
}

// ---------------------------------------------------------------------------
// prep: WbT (transpose+convert Wmap, append bmap), Whh/Who/x -> bf16
// ---------------------------------------------------------------------------
__global__ void k_prep(const float* __restrict__ x, const float* __restrict__ Wmap,
                       const float* __restrict__ bmap, const float* __restrict__ Whh,
                       const float* __restrict__ Who,
                       ushort_t* WbT, ushort_t* Whhb, ushort_t* Whob, ushort_t* xbf) {
    __shared__ __align__(16) float tl[32 * 257];
    const int tid = threadIdx.x;
    const int bid = blockIdx.x;
    if (bid < 512) {
        const int n = bid;
        for (int p = 0; p < 2; ++p) {
            if (p) __syncthreads();
#pragma unroll
            for (int k = 0; k < 32; ++k)
                tl[k * 257 + tid] = Wmap[(size_t)(n * 64 + p * 32 + k) * 256 + tid];
            __syncthreads();
#pragma unroll
            for (int k2 = 0; k2 < 32; ++k2) {
                int o = k2 * 256 + tid;
                int il = o & 31, c = o >> 5;
                WbT[(size_t)n * 16448 + c * 64 + p * 32 + il] = f2bf(tl[il * 257 + c]);
            }
        }
        if (tid < 64) WbT[(size_t)n * 16448 + 16384 + tid] = f2bf(bmap[n * 64 + tid]);
    } else if (bid < 528) {
        size_t base = (size_t)(bid - 512) * 16384;
#pragma unroll
        for (int k = 0; k < 64; ++k) { size_t i = base + k * 256 + tid; Whhb[i] = f2bf(Whh[i]); }
    } else if (bid < 532) {
        size_t base = (size_t)(bid - 528) * 16384;
#pragma unroll
        for (int k = 0; k < 64; ++k) { size_t i = base + k * 256 + tid; Whob[i] = f2bf(Who[i]); }
    } else {
        size_t base = (size_t)(bid - 532) * 4096;
#pragma unroll
        for (int k = 0; k < 16; ++k) { size_t i = base + k * 256 + tid; xbf[i] = f2bf(x[i]); }
    }
}

// ---------------------------------------------------------------------------
// Xc[m][j] = bic[j]+bcc[j] + sum_i Wic[j][i]*x[m][i]
// ---------------------------------------------------------------------------
__global__ __launch_bounds__(256, 1) void k_xc(const float* __restrict__ x,
                                               const float* __restrict__ Wic,
                                               const float* __restrict__ bic,
                                               const float* __restrict__ bcc,
                                               float* __restrict__ Xc) {
    __shared__ __align__(16) float xs[64 * 64];
    const int tid = threadIdx.x;
    const int m0 = blockIdx.x * 64;
#pragma unroll
    for (int k = 0; k < 16; ++k) xs[k * 256 + tid] = x[(size_t)m0 * 64 + k * 256 + tid];
    float wv[64];
#pragma unroll
    for (int q = 0; q < 16; ++q) {
        float4 f = *(const float4*)(Wic + tid * 64 + q * 4);
        wv[q * 4] = f.x; wv[q * 4 + 1] = f.y; wv[q * 4 + 2] = f.z; wv[q * 4 + 3] = f.w;
    }
    const float bias = bic[tid] + bcc[tid];
    __syncthreads();
    for (int mr = 0; mr < 64; ++mr) {
        float acc = bias;
#pragma unroll
        for (int q = 0; q < 16; ++q) {
            float4 xv = *(const float4*)(xs + mr * 64 + q * 4);
            acc = fmaf(wv[q * 4], xv.x, acc);
            acc = fmaf(wv[q * 4 + 1], xv.y, acc);
            acc = fmaf(wv[q * 4 + 2], xv.z, acc);
            acc = fmaf(wv[q * 4 + 3], xv.w, acc);
        }
        Xc[(size_t)(m0 + mr) * 256 + tid] = acc;
    }
}

// ---------------------------------------------------------------------------
// Sequential ctx recurrence as batched MFMA. 8 blocks x 256 thr; block g owns
// samples b in [g*16, g*16+16). D[m=j(256)][n=b(16)] = Wcc(A,regs) x ctx(B,LDS).
// Per step: 8 B-frag reads + 32 MFMA per wave; Xc prefetched one step ahead.
// Writes CTXT[c][t*128+b] fp32 (scale input of k_big) + final ctx to out tail.
// ---------------------------------------------------------------------------
__global__ __launch_bounds__(256, 1) void k_rec2(const float* __restrict__ Wcc,
                                                 const float* __restrict__ Xc,
                                                 float* __restrict__ CTXT,
                                                 float* __restrict__ ctx_out) {
    __shared__ __align__(16) ushort_t ctxs[16 * 256];  // frag-major: byte = k8*256 + b*16
    const int tid = threadIdx.x, lane = tid & 63, w = tid >> 6;
    const int l15 = lane & 15, quad = lane >> 4;
    const int g = blockIdx.x;

    // Wcc A-fragments: j = w*64 + mt*16 + l15, k(=c) = kb*32 + quad*8 + e
    short8 wf[4][8];
#pragma unroll
    for (int mt = 0; mt < 4; ++mt)
#pragma unroll
        for (int kb = 0; kb < 8; ++kb) {
            const float* src = Wcc + (size_t)(w * 64 + mt * 16 + l15) * 256 + kb * 32 + quad * 8;
            float4 a = *(const float4*)src;
            float4 b = *(const float4*)(src + 4);
            short8 s;
            s[0] = (short)f2bf(a.x); s[1] = (short)f2bf(a.y);
            s[2] = (short)f2bf(a.z); s[3] = (short)f2bf(a.w);
            s[4] = (short)f2bf(b.x); s[5] = (short)f2bf(b.y);
            s[6] = (short)f2bf(b.z); s[7] = (short)f2bf(b.w);
            wf[mt][kb] = s;
        }
    // zero ctx LDS (ctx_0 = 0)
    *(uint4*)(ctxs + tid * 16) = (uint4){0, 0, 0, 0};
    *(uint4*)(ctxs + tid * 16 + 8) = (uint4){0, 0, 0, 0};

    float4 y[4];
#pragma unroll
    for (int mt = 0; mt < 4; ++mt) y[mt] = (float4){0.f, 0.f, 0.f, 0.f};

    // prefetch Xc frags for t=0: Xc[(t*128+g*16+l15)][w*64+mt*16+quad*4 ..+3]
    float4 xc[4];
#pragma unroll
    for (int mt = 0; mt < 4; ++mt)
        xc[mt] = *(const float4*)(Xc + (size_t)(g * 16 + l15) * 256 + w * 64 + mt * 16 + quad * 4);
    __syncthreads();

#pragma unroll 1
    for (int t = 0; t < 256; ++t) {
        // write ctx entering step t (fp32) to CTXT[c][t*128+b]
#pragma unroll
        for (int mt = 0; mt < 4; ++mt) {
            const int j = w * 64 + mt * 16 + quad * 4;
#pragma unroll
            for (int r = 0; r < 4; ++r)
                CTXT[(size_t)(j + r) * 32768 + t * 128 + g * 16 + l15] = y[mt][r];
        }
        // MFMA: acc[mt] = Wcc-rows x ctx
        floatx4 acc[4];
#pragma unroll
        for (int mt = 0; mt < 4; ++mt) acc[mt] = (floatx4){0.f, 0.f, 0.f, 0.f};
#pragma unroll
        for (int kb = 0; kb < 8; ++kb) {
            short8 bf = *(const short8*)((const char*)ctxs + (kb * 4 + quad) * 256 + l15 * 16);
#pragma unroll
            for (int mt = 0; mt < 4; ++mt)
                acc[mt] = __builtin_amdgcn_mfma_f32_16x16x32_bf16(wf[mt][kb], bf, acc[mt], 0, 0, 0);
        }
        // prefetch next Xc
        const int tn = (t < 255) ? (t + 1) : 255;
        float4 xcn[4];
#pragma unroll
        for (int mt = 0; mt < 4; ++mt)
            xcn[mt] = *(const float4*)(Xc + (size_t)(tn * 128 + g * 16 + l15) * 256 + w * 64 + mt * 16 + quad * 4);
        // y = relu(acc + xc)
#pragma unroll
        for (int mt = 0; mt < 4; ++mt) {
            y[mt].x = fmaxf(acc[mt][0] + xc[mt].x, 0.f);
            y[mt].y = fmaxf(acc[mt][1] + xc[mt].y, 0.f);
            y[mt].z = fmaxf(acc[mt][2] + xc[mt].z, 0.f);
            y[mt].w = fmaxf(acc[mt][3] + xc[mt].w, 0.f);
        }
        __syncthreads();   // all B-frag reads of ctx_t done
        if (t < 255) {
            // write bf16 ctx_{t+1}: lane holds c = w*64+mt*16+quad*4+(0..3), b=l15
#pragma unroll
            for (int mt = 0; mt < 4; ++mt) {
                const int c0 = w * 64 + mt * 16 + quad * 4;
                short4v s4;
                s4[0] = (short)f2bf(y[mt].x); s4[1] = (short)f2bf(y[mt].y);
                s4[2] = (short)f2bf(y[mt].z); s4[3] = (short)f2bf(y[mt].w);
                *(short4v*)((char*)ctxs + (c0 >> 3) * 256 + l15 * 16 + (c0 & 7) * 2) = s4;
            }
        }
        __syncthreads();
#pragma unroll
        for (int mt = 0; mt < 4; ++mt) xc[mt] = xcn[mt];
    }
    // final ctx (t=256) -> out tail [b][c]
#pragma unroll
    for (int mt = 0; mt < 4; ++mt) {
        const int j = w * 64 + mt * 16 + quad * 4;
#pragma unroll
        for (int r = 0; r < 4; ++r)
            ctx_out[(size_t)(g * 16 + l15) * 256 + j + r] = y[mt][r];
    }
}

// ---------------------------------------------------------------------------
// BIG GEMM: h = relu( sum_c ctx[m,c]*S_c + S_bias ), M=32768,N=512,K=16448.
// 128x128 tile, 4 waves. A (x rows) in regs once. B staged via
// global_load_lds(16B) into XOR-swizzled unpadded LDS (2-way reads = free).
// grid (256,4) x 256; launch_bounds(256,4) -> 4 blocks/CU, one balanced round.
// ---------------------------------------------------------------------------
__global__ __launch_bounds__(256, 4) void k_big(const ushort_t* __restrict__ xbf,
                                                const ushort_t* __restrict__ WbT,
                                                const float* __restrict__ CTXT,
                                                ushort_t* __restrict__ hbf) {
    __shared__ __align__(16) ushort_t Bt[128 * 64];   // 16KB, swizzled granules
    const int tid = threadIdx.x;
    const int lane = tid & 63, w = tid >> 6;
    const int wm = w & 1, wn = w >> 1;
    const int l15 = lane & 15, quad = lane >> 4;
    const int m0 = blockIdx.x * 128, n0 = blockIdx.y * 128;

    short8 afr[4][2];
#pragma unroll
    for (int mt = 0; mt < 4; ++mt)
#pragma unroll
        for (int ks = 0; ks < 2; ++ks)
            afr[mt][ks] = *(const short8*)(xbf + (size_t)(m0 + wm * 64 + mt * 16 + l15) * 64 + ks * 32 + quad * 8);

    floatx4 acc[4][4];
#pragma unroll
    for (int i = 0; i < 4; ++i)
#pragma unroll
        for (int j = 0; j < 4; ++j) acc[i][j] = (floatx4){0.f, 0.f, 0.f, 0.f};

    // staging: granule G = w*256 + q*64 + lane; nr=G>>3; slot=G&7; k8=slot^(nr&7)
    const ushort_t* gq[4];
    ushort_t* lq[4];
#pragma unroll
    for (int q = 0; q < 4; ++q) {
        const int G = w * 256 + q * 64 + lane;
        const int nr = G >> 3;
        const int k8 = (G & 7) ^ (nr & 7);
        gq[q] = WbT + (size_t)(n0 + nr) * 16448 + k8 * 8;
        lq[q] = Bt + w * 2048 + q * 512;   // wave-uniform base; lane*16B auto
    }
    const int swo0 = (quad ^ (l15 & 7)) * 16;
    const int swo1 = swo0 ^ 64;

#pragma unroll
    for (int q = 0; q < 4; ++q) glds16(gq[q], lq[q]);

    const floatx4 fz = {0.f, 0.f, 0.f, 0.f};
    for (int cb = 0; cb < 257; ++cb) {
        __syncthreads();   // vmcnt drain: tile cb resident
        floatx4 sc[4];
        if (cb < 256) {
#pragma unroll
            for (int mt = 0; mt < 4; ++mt)
                sc[mt] = *(const floatx4*)(CTXT + (size_t)cb * 32768 + m0 + wm * 64 + mt * 16 + quad * 4);
        } else {
#pragma unroll
            for (int mt = 0; mt < 4; ++mt) sc[mt] = (floatx4){1.f, 1.f, 1.f, 1.f};
        }
#pragma unroll
        for (int nt = 0; nt < 4; ++nt) {
            const int nr = wn * 64 + nt * 16 + l15;
            const char* bp = (const char*)Bt + nr * 128;
            short8 b0 = *(const short8*)(bp + swo0);
            short8 b1 = *(const short8*)(bp + swo1);
#pragma unroll
            for (int mt = 0; mt < 4; ++mt) {
                floatx4 t0 = __builtin_amdgcn_mfma_f32_16x16x32_bf16(afr[mt][0], b0, fz, 0, 0, 0);
                t0 = __builtin_amdgcn_mfma_f32_16x16x32_bf16(afr[mt][1], b1, t0, 0, 0, 0);
                acc[mt][nt] += sc[mt] * t0;
            }
        }
        __syncthreads();   // reads done, safe to overwrite
        if (cb < 256) {
            const int koff = (cb + 1) * 64;
#pragma unroll
            for (int q = 0; q < 4; ++q) glds16(gq[q] + koff, lq[q]);
        }
    }
#pragma unroll
    for (int mt = 0; mt < 4; ++mt)
#pragma unroll
        for (int nt = 0; nt < 4; ++nt) {
            const int col = n0 + wn * 64 + nt * 16 + l15;
#pragma unroll
            for (int r = 0; r < 4; ++r) {
                const int row = m0 + wm * 64 + mt * 16 + quad * 4 + r;
                hbf[(size_t)row * 512 + col] = f2bf(fmaxf(acc[mt][nt][r], 0.f));
            }
        }
}

// ---------------------------------------------------------------------------
// Generic bf16 NT GEMM: C[m,n] = sum_k A[m,k]*B[n,k] + bias[n]
// ---------------------------------------------------------------------------
template <bool OUTF32>
__global__ __launch_bounds__(256, 2) void k_gemm_nt(const ushort_t* __restrict__ A,
                                                    const ushort_t* __restrict__ Bm,
                                                    const float* __restrict__ bias,
                                                    ushort_t* __restrict__ outb,
                                                    float* __restrict__ outf,
                                                    int K, int Nst) {
    __shared__ __align__(16) ushort_t At[128 * 72];
    __shared__ __align__(16) ushort_t Bt[128 * 72];
    const int tid = threadIdx.x;
    const int lane = tid & 63, w = tid >> 6;
    const int wm = w & 1, wn = w >> 1;
    const int l15 = lane & 15, quad = lane >> 4;
    const int m0 = blockIdx.x * 128, n0 = blockIdx.y * 128;

    const int r_l = tid >> 1, kh = (tid & 1) * 32;
    const ushort_t* gA = A + (size_t)(m0 + r_l) * K + kh;
    const ushort_t* gB = Bm + (size_t)(n0 + r_l) * K + kh;
    ushort_t* lA = &At[r_l * 72 + kh];
    ushort_t* lB = &Bt[r_l * 72 + kh];

    uint4 ra0 = *(const uint4*)(gA + 0), ra1 = *(const uint4*)(gA + 8);
    uint4 ra2 = *(const uint4*)(gA + 16), ra3 = *(const uint4*)(gA + 24);
    uint4 rb0 = *(const uint4*)(gB + 0), rb1 = *(const uint4*)(gB + 8);
    uint4 rb2 = *(const uint4*)(gB + 16), rb3 = *(const uint4*)(gB + 24);

    floatx4 acc[4][4];
#pragma unroll
    for (int i = 0; i < 4; ++i)
#pragma unroll
        for (int j = 0; j < 4; ++j) acc[i][j] = (floatx4){0.f, 0.f, 0.f, 0.f};

    const int niter = K >> 6;
    for (int kb = 0; kb < niter; ++kb) {
        __syncthreads();
        *(uint4*)(lA + 0) = ra0;  *(uint4*)(lA + 8) = ra1;
        *(uint4*)(lA + 16) = ra2; *(uint4*)(lA + 24) = ra3;
        *(uint4*)(lB + 0) = rb0;  *(uint4*)(lB + 8) = rb1;
        *(uint4*)(lB + 16) = rb2; *(uint4*)(lB + 24) = rb3;
        __syncthreads();
        if (kb + 1 < niter) {
            const ushort_t* ga = gA + (size_t)(kb + 1) * 64;
            const ushort_t* gb = gB + (size_t)(kb + 1) * 64;
            ra0 = *(const uint4*)(ga + 0);  ra1 = *(const uint4*)(ga + 8);
            ra2 = *(const uint4*)(ga + 16); ra3 = *(const uint4*)(ga + 24);
            rb0 = *(const uint4*)(gb + 0);  rb1 = *(const uint4*)(gb + 8);
            rb2 = *(const uint4*)(gb + 16); rb3 = *(const uint4*)(gb + 24);
        }
        short8 av[4][2];
#pragma unroll
        for (int mt = 0; mt < 4; ++mt) {
            const int mr = wm * 64 + mt * 16 + l15;
            av[mt][0] = *(const short8*)(&At[mr * 72 + quad * 8]);
            av[mt][1] = *(const short8*)(&At[mr * 72 + 32 + quad * 8]);
        }
#pragma unroll
        for (int nt = 0; nt < 4; ++nt) {
            const int nr = wn * 64 + nt * 16 + l15;
            short8 b0 = *(const short8*)(&Bt[nr * 72 + quad * 8]);
            short8 b1 = *(const short8*)(&Bt[nr * 72 + 32 + quad * 8]);
#pragma unroll
            for (int mt = 0; mt < 4; ++mt) {
                acc[mt][nt] = __builtin_amdgcn_mfma_f32_16x16x32_bf16(av[mt][0], b0, acc[mt][nt], 0, 0, 0);
                acc[mt][nt] = __builtin_amdgcn_mfma_f32_16x16x32_bf16(av[mt][1], b1, acc[mt][nt], 0, 0, 0);
            }
        }
    }
#pragma unroll
    for (int mt = 0; mt < 4; ++mt)
#pragma unroll
        for (int nt = 0; nt < 4; ++nt) {
            const int col = n0 + wn * 64 + nt * 16 + l15;
            const float bb = bias[col];
#pragma unroll
            for (int r = 0; r < 4; ++r) {
                const int row = m0 + wm * 64 + mt * 16 + quad * 4 + r;
                const float v = acc[mt][nt][r] + bb;
                if (OUTF32) outf[(size_t)row * Nst + col] = v;
                else        outb[(size_t)row * Nst + col] = f2bf(v);
            }
        }
}

// ---------------------------------------------------------------------------
// LayerNorm + residual: z = h + relu( LN(hn)*g + b ), in-place over hbf.
// ---------------------------------------------------------------------------
__global__ __launch_bounds__(256, 1) void k_ln(const ushort_t* __restrict__ hn,
                                               ushort_t* __restrict__ h,
                                               const float* __restrict__ g,
                                               const float* __restrict__ bb) {
    const int tid = threadIdx.x;
    const int lane = tid & 63;
    const int row = blockIdx.x * 4 + (tid >> 6);
    const uint4 hv = *(const uint4*)(hn + (size_t)row * 512 + lane * 8);
    float f[8];
    f[0] = blo(hv.x); f[1] = bhi(hv.x); f[2] = blo(hv.y); f[3] = bhi(hv.y);
    f[4] = blo(hv.z); f[5] = bhi(hv.z); f[6] = blo(hv.w); f[7] = bhi(hv.w);
    float s = 0.f, s2 = 0.f;
#pragma unroll
    for (int j = 0; j < 8; ++j) { s += f[j]; s2 = fmaf(f[j], f[j], s2); }
#pragma unroll
    for (int o = 32; o >= 1; o >>= 1) { s += __shfl_xor(s, o, 64); s2 += __shfl_xor(s2, o, 64); }
    const float mu = s * (1.f / 512.f);
    const float var = s2 * (1.f / 512.f) - mu * mu;
    const float rs = rsqrtf(var + 1e-5f);
    const uint4 hh = *(const uint4*)(h + (size_t)row * 512 + lane * 8);
    float hf[8];
    hf[0] = blo(hh.x); hf[1] = bhi(hh.x); hf[2] = blo(hh.y); hf[3] = bhi(hh.y);
    hf[4] = blo(hh.z); hf[5] = bhi(hh.z); hf[6] = blo(hh.w); hf[7] = bhi(hh.w);
    float4 g0 = *(const float4*)(g + lane * 8);  float4 g1 = *(const float4*)(g + lane * 8 + 4);
    float4 b0 = *(const float4*)(bb + lane * 8); float4 b1 = *(const float4*)(bb + lane * 8 + 4);
    const float gv[8] = {g0.x, g0.y, g0.z, g0.w, g1.x, g1.y, g1.z, g1.w};
    const float bv[8] = {b0.x, b0.y, b0.z, b0.w, b1.x, b1.y, b1.z, b1.w};
    float z[8];
#pragma unroll
    for (int j = 0; j < 8; ++j)
        z[j] = hf[j] + fmaxf((f[j] - mu) * rs * gv[j] + bv[j], 0.f);
    uint4 o;
    o.x = pack2(z[0], z[1]); o.y = pack2(z[2], z[3]);
    o.z = pack2(z[4], z[5]); o.w = pack2(z[6], z[7]);
    *(uint4*)(h + (size_t)row * 512 + lane * 8) = o;
}

// ---------------------------------------------------------------------------
extern "C" void kernel_launch(void* const* d_in, const int* in_sizes, int n_in,
                              void* d_out, int out_size, void* d_ws, size_t ws_size,
                              hipStream_t stream) {
    const float* x    = (const float*)d_in[0];
    const float* Wcc  = (const float*)d_in[1];
    const float* bcc  = (const float*)d_in[2];
    const float* Wic  = (const float*)d_in[3];
    const float* bic  = (const float*)d_in[4];
    const float* Wmap = (const float*)d_in[5];
    const float* bmap = (const float*)d_in[6];
    const float* Whh  = (const float*)d_in[7];
    const float* bhh  = (const float*)d_in[8];
    const float* ln_g = (const float*)d_in[9];
    const float* ln_b = (const float*)d_in[10];
    const float* Who  = (const float*)d_in[11];
    const float* bho  = (const float*)d_in[12];
    float* out = (float*)d_out;

    char* wsb = (char*)d_ws;
    ushort_t* WbT  = (ushort_t*)(wsb);                    // 16,842,752 B
    ushort_t* Whhb = (ushort_t*)(wsb + 16842752);         //    524,288
    ushort_t* Whob = (ushort_t*)(wsb + 17367040);         //    131,072
    ushort_t* xbf  = (ushort_t*)(wsb + 17498112);         //  4,194,304
    float*    Xc   = (float*)   (wsb + 21692416);         // 33,554,432
    float*    CTXT = (float*)   (wsb + 55246848);         // 33,554,432
    ushort_t* hbf  = (ushort_t*)(wsb + 88801280);         // 33,554,432 (h, then z in-place)
    ushort_t* hnbf = (ushort_t*)(wsb + 122355712);        // 33,554,432 -> total ~156 MB

    k_prep<<<1044, 256, 0, stream>>>(x, Wmap, bmap, Whh, Who, WbT, Whhb, Whob, xbf);
    k_xc<<<512, 256, 0, stream>>>(x, Wic, bic, bcc, Xc);
    k_rec2<<<8, 256, 0, stream>>>(Wcc, Xc, CTXT, out + 4194304);
    k_big<<<dim3(256, 4), 256, 0, stream>>>(xbf, WbT, CTXT, hbf);
    k_gemm_nt<false><<<dim3(256, 4), 256, 0, stream>>>(hbf, Whhb, bhh, hnbf, nullptr, 512, 512);
    k_ln<<<8192, 256, 0, stream>>>(hnbf, hbf, ln_g, ln_b);
    k_gemm_nt<true><<<dim3(256, 1), 256, 0, stream>>>(hbf, Whob, bho, nullptr, out, 512, 128);
}

// Round 3
// 956.176 us; speedup vs baseline: 1.8095x; 1.1801x over previous
//
#include <hip/hip_runtime.h>

// ---------------------------------------------------------------------------
// InputMapCTRNN: T=256, B=128, I=64, C=256, H=512, O=128, ALPHA=1, EPS=1e-5
//
// h[t,b,n] = relu( sum_c ctx[t,b,c]*S_c + S_bias ),
//   S_c[m,n] = sum_i x[m,i]*WbT[n, c*64+i]  -> one MFMA GEMM M=32768,N=512,
//   K=16448 with fp32 per-c scaling of partials.
// Recurrence: K=320 batched MFMA  ctx' = relu([Wcc|Wic] @ [ctx;x] + bias),
//   fused in one grid with the prep blocks (prep hides under recurrence).
// k_big: BK=128/barrier, 512-thr blocks, glds(16B), XCD-aware by-swizzle.
// ---------------------------------------------------------------------------

typedef unsigned int  uint_t;
typedef unsigned short ushort_t;
typedef __attribute__((ext_vector_type(8))) short  short8;
typedef __attribute__((ext_vector_type(4))) short  short4v;
typedef __attribute__((ext_vector_type(4))) float  floatx4;

__device__ __forceinline__ ushort_t f2bf(float f) {
    uint_t u = __float_as_uint(f);
    u = (u + 0x7fffu + ((u >> 16) & 1u)) >> 16;   // RNE
    return (ushort_t)u;
}
__device__ __forceinline__ uint_t pack2(float a, float b) {
    return (uint_t)f2bf(a) | ((uint_t)f2bf(b) << 16);
}
__device__ __forceinline__ float blo(uint_t u) { return __uint_as_float(u << 16); }
__device__ __forceinline__ float bhi(uint_t u) { return __uint_as_float(u & 0xffff0000u); }

__device__ __forceinline__ void glds16(const void* g, void* l) {
    __builtin_amdgcn_global_load_lds(
        (const __attribute__((address_space(1))) unsigned int*)g,
        (__attribute__((address_space(3))) unsigned int*)l, 16, 0, 0);
}

// ---------------------------------------------------------------------------
// FUSED: blocks 0..7 = sequential ctx recurrence (K=320 MFMA, 1 barrier/step,
// LDS double-buffer, x read fp32 from input). blocks 8..1051 = prep (WbT
// transpose+cvt, Whh/Who/x -> bf16) — independent, hides under recurrence.
// ---------------------------------------------------------------------------
__global__ __launch_bounds__(256, 1) void k_fused(
        const float* __restrict__ x, const float* __restrict__ Wcc,
        const float* __restrict__ bcc, const float* __restrict__ Wic,
        const float* __restrict__ bic, const float* __restrict__ Wmap,
        const float* __restrict__ bmap, const float* __restrict__ Whh,
        const float* __restrict__ Who,
        ushort_t* WbT, ushort_t* Whhb, ushort_t* Whob, ushort_t* xbf,
        float* __restrict__ CTXT, float* __restrict__ ctx_out) {
    __shared__ __align__(16) char smem[32896];   // union: prep 32896 B / rec 20480 B
    const int tid = threadIdx.x;
    const int bid = blockIdx.x;

    if (bid >= 8) {
        const int pb = bid - 8;
        if (pb < 512) {                      // WbT[n][c*64+i] = Wmap[n*64+i][c]
            float* tl = (float*)smem;        // 32*257 floats
            const int n = pb;
            for (int p = 0; p < 2; ++p) {
                if (p) __syncthreads();
#pragma unroll
                for (int k = 0; k < 32; ++k)
                    tl[k * 257 + tid] = Wmap[(size_t)(n * 64 + p * 32 + k) * 256 + tid];
                __syncthreads();
#pragma unroll
                for (int k2 = 0; k2 < 32; ++k2) {
                    int o = k2 * 256 + tid;
                    int il = o & 31, c = o >> 5;
                    WbT[(size_t)n * 16448 + c * 64 + p * 32 + il] = f2bf(tl[il * 257 + c]);
                }
            }
            if (tid < 64) WbT[(size_t)n * 16448 + 16384 + tid] = f2bf(bmap[n * 64 + tid]);
        } else if (pb < 528) {
            size_t base = (size_t)(pb - 512) * 16384;
#pragma unroll
            for (int k = 0; k < 64; ++k) { size_t i = base + k * 256 + tid; Whhb[i] = f2bf(Whh[i]); }
        } else if (pb < 532) {
            size_t base = (size_t)(pb - 528) * 16384;
#pragma unroll
            for (int k = 0; k < 64; ++k) { size_t i = base + k * 256 + tid; Whob[i] = f2bf(Who[i]); }
        } else {
            size_t base = (size_t)(pb - 532) * 4096;
#pragma unroll
            for (int k = 0; k < 16; ++k) { size_t i = base + k * 256 + tid; xbf[i] = f2bf(x[i]); }
        }
        return;
    }

    // ---------------- recurrence: block g owns samples [g*16, g*16+16) ------
    // LDS buffer (per parity): 40 granule-rows x 256 B; row r = k>>3 holds
    // B-frag bytes [b*16 + (k&7)*2]; k 0..255 = ctx (bf16), k 256..319 = x.
    char* bufs = smem;                          // 2 x 10240 B
    const int g = bid;
    const int lane = tid & 63, w = tid >> 6;
    const int l15 = lane & 15, quad = lane >> 4;
    const int bq = tid >> 4, o4 = tid & 15;     // x-staging role

    // A-fragments: Wcc (kb 0..7) + Wic (kb 8..9); row j = w*64+mt*16+l15
    short8 wf[4][8], wi[4][2];
#pragma unroll
    for (int mt = 0; mt < 4; ++mt) {
        const int j = w * 64 + mt * 16 + l15;
#pragma unroll
        for (int kb = 0; kb < 8; ++kb) {
            const float* src = Wcc + (size_t)j * 256 + kb * 32 + quad * 8;
            float4 a = *(const float4*)src;
            float4 b = *(const float4*)(src + 4);
            short8 s;
            s[0] = (short)f2bf(a.x); s[1] = (short)f2bf(a.y);
            s[2] = (short)f2bf(a.z); s[3] = (short)f2bf(a.w);
            s[4] = (short)f2bf(b.x); s[5] = (short)f2bf(b.y);
            s[6] = (short)f2bf(b.z); s[7] = (short)f2bf(b.w);
            wf[mt][kb] = s;
        }
#pragma unroll
        for (int kb = 0; kb < 2; ++kb) {
            const float* src = Wic + (size_t)j * 64 + kb * 32 + quad * 8;
            float4 a = *(const float4*)src;
            float4 b = *(const float4*)(src + 4);
            short8 s;
            s[0] = (short)f2bf(a.x); s[1] = (short)f2bf(a.y);
            s[2] = (short)f2bf(a.z); s[3] = (short)f2bf(a.w);
            s[4] = (short)f2bf(b.x); s[5] = (short)f2bf(b.y);
            s[6] = (short)f2bf(b.z); s[7] = (short)f2bf(b.w);
            wi[mt][kb] = s;
        }
    }
    // bias per C/D slot: j0 = w*64+mt*16+quad*4
    float4 bias[4];
#pragma unroll
    for (int mt = 0; mt < 4; ++mt) {
        const int j0 = w * 64 + mt * 16 + quad * 4;
        float4 b1 = *(const float4*)(bic + j0);
        float4 b2 = *(const float4*)(bcc + j0);
        bias[mt] = (float4){b1.x + b2.x, b1.y + b2.y, b1.z + b2.z, b1.w + b2.w};
    }
    // init buf0: ctx=0 (granule rows 0..31), x_0 (rows 32..39)
    *(uint4*)(bufs + tid * 16) = (uint4){0, 0, 0, 0};
    *(uint4*)(bufs + (tid + 256) * 16) = (uint4){0, 0, 0, 0};
    {
        float4 xv = *(const float4*)(x + (size_t)(g * 16 + bq) * 64 + o4 * 4);
        short4v s4;
        s4[0] = (short)f2bf(xv.x); s4[1] = (short)f2bf(xv.y);
        s4[2] = (short)f2bf(xv.z); s4[3] = (short)f2bf(xv.w);
        *(short4v*)(bufs + (32 + (o4 >> 1)) * 256 + bq * 16 + (o4 & 1) * 8) = s4;
    }
    float4 y[4];
#pragma unroll
    for (int mt = 0; mt < 4; ++mt) y[mt] = (float4){0.f, 0.f, 0.f, 0.f};
    __syncthreads();

    int p = 0;
#pragma unroll 1
    for (int t = 0; t < 256; ++t) {
        char* bp = bufs + p * 10240;
        char* bn = bufs + (p ^ 1) * 10240;
        // CTXT[c][t*128 + b] = ctx entering step t (= y)
#pragma unroll
        for (int mt = 0; mt < 4; ++mt) {
            const int j0 = w * 64 + mt * 16 + quad * 4;
#pragma unroll
            for (int r = 0; r < 4; ++r)
                CTXT[(size_t)(j0 + r) * 32768 + t * 128 + g * 16 + l15] = (&y[mt].x)[r];
        }
        // prefetch x_{t+1}
        float4 xv;
        if (t < 255)
            xv = *(const float4*)(x + (size_t)((t + 1) * 128 + g * 16 + bq) * 64 + o4 * 4);
        // MFMA over K=320
        floatx4 acc[4];
#pragma unroll
        for (int mt = 0; mt < 4; ++mt) acc[mt] = (floatx4){0.f, 0.f, 0.f, 0.f};
#pragma unroll
        for (int kb = 0; kb < 8; ++kb) {
            short8 bf = *(const short8*)(bp + (kb * 4 + quad) * 256 + l15 * 16);
#pragma unroll
            for (int mt = 0; mt < 4; ++mt)
                acc[mt] = __builtin_amdgcn_mfma_f32_16x16x32_bf16(wf[mt][kb], bf, acc[mt], 0, 0, 0);
        }
#pragma unroll
        for (int kb = 0; kb < 2; ++kb) {
            short8 bf = *(const short8*)(bp + ((8 + kb) * 4 + quad) * 256 + l15 * 16);
#pragma unroll
            for (int mt = 0; mt < 4; ++mt)
                acc[mt] = __builtin_amdgcn_mfma_f32_16x16x32_bf16(wi[mt][kb], bf, acc[mt], 0, 0, 0);
        }
        // y = relu(acc + bias); write ctx_{t+1} + x_{t+1} to other buffer
#pragma unroll
        for (int mt = 0; mt < 4; ++mt) {
            y[mt].x = fmaxf(acc[mt][0] + bias[mt].x, 0.f);
            y[mt].y = fmaxf(acc[mt][1] + bias[mt].y, 0.f);
            y[mt].z = fmaxf(acc[mt][2] + bias[mt].z, 0.f);
            y[mt].w = fmaxf(acc[mt][3] + bias[mt].w, 0.f);
        }
        if (t < 255) {
#pragma unroll
            for (int mt = 0; mt < 4; ++mt) {
                const int c0 = w * 64 + mt * 16 + quad * 4;
                short4v s4;
                s4[0] = (short)f2bf(y[mt].x); s4[1] = (short)f2bf(y[mt].y);
                s4[2] = (short)f2bf(y[mt].z); s4[3] = (short)f2bf(y[mt].w);
                *(short4v*)(bn + (c0 >> 3) * 256 + l15 * 16 + (c0 & 7) * 2) = s4;
            }
            short4v s4;
            s4[0] = (short)f2bf(xv.x); s4[1] = (short)f2bf(xv.y);
            s4[2] = (short)f2bf(xv.z); s4[3] = (short)f2bf(xv.w);
            *(short4v*)(bn + (32 + (o4 >> 1)) * 256 + bq * 16 + (o4 & 1) * 8) = s4;
        }
        __syncthreads();
        p ^= 1;
    }
    // final ctx -> out tail [b][c]
#pragma unroll
    for (int mt = 0; mt < 4; ++mt) {
        const int j0 = w * 64 + mt * 16 + quad * 4;
#pragma unroll
        for (int r = 0; r < 4; ++r)
            ctx_out[(size_t)(g * 16 + l15) * 256 + j0 + r] = (&y[mt].x)[r];
    }
}

// ---------------------------------------------------------------------------
// BIG GEMM: M=32768,N=512,K=16448 with per-c fp32 scale. 512 thr / 8 waves,
// tile 128x128, BK=128 per barrier (32 KB LDS, XOR-swizzled, glds 16B).
// 1D grid 1024, XCD swizzle: by = (g&7)&3 so each XCD streams ONE WbT slice.
// ---------------------------------------------------------------------------
__global__ __launch_bounds__(512, 4) void k_big(const ushort_t* __restrict__ xbf,
                                                const ushort_t* __restrict__ WbT,
                                                const float* __restrict__ CTXT,
                                                ushort_t* __restrict__ hbf) {
    __shared__ __align__(16) ushort_t Bt[128 * 128];   // 32 KB
    const int tid = threadIdx.x;
    const int lane = tid & 63, w = tid >> 6;           // 8 waves
    const int wm = w & 3, wn = w >> 2;                 // wave tile 32m x 64n
    const int l15 = lane & 15, quad = lane >> 4;
    const int gidx = blockIdx.x;
    const int by = gidx & 3;                           // xcd = gidx&7 -> by const/XCD
    const int bx = (gidx >> 3) * 2 + ((gidx >> 2) & 1);
    const int m0 = bx * 128, n0 = by * 128;

    short8 afr[2][2];
#pragma unroll
    for (int mt = 0; mt < 2; ++mt)
#pragma unroll
        for (int ks = 0; ks < 2; ++ks)
            afr[mt][ks] = *(const short8*)(xbf + (size_t)(m0 + wm * 32 + mt * 16 + l15) * 64 + ks * 32 + quad * 8);

    floatx4 acc[2][4];
#pragma unroll
    for (int i = 0; i < 2; ++i)
#pragma unroll
        for (int j = 0; j < 4; ++j) acc[i][j] = (floatx4){0.f, 0.f, 0.f, 0.f};

    // staging: granule G = w*256 + q*64 + lane; nr=G>>4; k8=(G&15)^(nr&15)
    const ushort_t* gq[4];
    ushort_t* lq[4];
#pragma unroll
    for (int q = 0; q < 4; ++q) {
        const int G = w * 256 + q * 64 + lane;
        const int nr = G >> 4;
        const int k8 = (G & 15) ^ (nr & 15);
        gq[q] = WbT + (size_t)(n0 + nr) * 16448 + k8 * 8;
        lq[q] = Bt + w * 2048 + q * 512;               // wave-uniform base
    }
#pragma unroll
    for (int q = 0; q < 4; ++q) glds16(gq[q], lq[q]);

    const floatx4 fz = {0.f, 0.f, 0.f, 0.f};
    for (int kk = 0; kk < 129; ++kk) {
        __syncthreads();                               // tile kk resident
        const bool last = (kk == 128);
        floatx4 sc[2][2];
        if (!last) {
#pragma unroll
            for (int h = 0; h < 2; ++h)
#pragma unroll
                for (int mt = 0; mt < 2; ++mt)
                    sc[h][mt] = *(const floatx4*)(CTXT + (size_t)(2 * kk + h) * 32768 + m0 + wm * 32 + mt * 16 + quad * 4);
        } else {
#pragma unroll
            for (int mt = 0; mt < 2; ++mt) sc[0][mt] = (floatx4){1.f, 1.f, 1.f, 1.f};
        }
        const int hmax = last ? 1 : 2;
        for (int h = 0; h < hmax; ++h) {
#pragma unroll
            for (int nt = 0; nt < 4; ++nt) {
                const int nr = wn * 64 + nt * 16 + l15;
                const char* bpr = (const char*)Bt + nr * 256;
                const int g0 = h * 8 + quad, g1 = h * 8 + 4 + quad;
                short8 b0 = *(const short8*)(bpr + ((g0 ^ l15) * 16));
                short8 b1 = *(const short8*)(bpr + ((g1 ^ l15) * 16));
#pragma unroll
                for (int mt = 0; mt < 2; ++mt) {
                    floatx4 t0 = __builtin_amdgcn_mfma_f32_16x16x32_bf16(afr[mt][0], b0, fz, 0, 0, 0);
                    t0 = __builtin_amdgcn_mfma_f32_16x16x32_bf16(afr[mt][1], b1, t0, 0, 0, 0);
                    acc[mt][nt] += sc[h][mt] * t0;
                }
            }
        }
        __syncthreads();                               // reads done
        if (!last) {
            const size_t koff = (size_t)(kk + 1) * 128;
#pragma unroll
            for (int q = 0; q < 4; ++q) glds16(gq[q] + koff, lq[q]);
        }
    }
#pragma unroll
    for (int mt = 0; mt < 2; ++mt)
#pragma unroll
        for (int nt = 0; nt < 4; ++nt) {
            const int col = n0 + wn * 64 + nt * 16 + l15;
#pragma unroll
            for (int r = 0; r < 4; ++r) {
                const int row = m0 + wm * 32 + mt * 16 + quad * 4 + r;
                hbf[(size_t)row * 512 + col] = f2bf(fmaxf(acc[mt][nt][r], 0.f));
            }
        }
}

// ---------------------------------------------------------------------------
// Generic bf16 NT GEMM: C[m,n] = sum_k A[m,k]*B[n,k] + bias[n]
// ---------------------------------------------------------------------------
template <bool OUTF32>
__global__ __launch_bounds__(256, 2) void k_gemm_nt(const ushort_t* __restrict__ A,
                                                    const ushort_t* __restrict__ Bm,
                                                    const float* __restrict__ bias,
                                                    ushort_t* __restrict__ outb,
                                                    float* __restrict__ outf,
                                                    int K, int Nst) {
    __shared__ __align__(16) ushort_t At[128 * 72];
    __shared__ __align__(16) ushort_t Bt[128 * 72];
    const int tid = threadIdx.x;
    const int lane = tid & 63, w = tid >> 6;
    const int wm = w & 1, wn = w >> 1;
    const int l15 = lane & 15, quad = lane >> 4;
    const int m0 = blockIdx.x * 128, n0 = blockIdx.y * 128;

    const int r_l = tid >> 1, kh = (tid & 1) * 32;
    const ushort_t* gA = A + (size_t)(m0 + r_l) * K + kh;
    const ushort_t* gB = Bm + (size_t)(n0 + r_l) * K + kh;
    ushort_t* lA = &At[r_l * 72 + kh];
    ushort_t* lB = &Bt[r_l * 72 + kh];

    uint4 ra0 = *(const uint4*)(gA + 0), ra1 = *(const uint4*)(gA + 8);
    uint4 ra2 = *(const uint4*)(gA + 16), ra3 = *(const uint4*)(gA + 24);
    uint4 rb0 = *(const uint4*)(gB + 0), rb1 = *(const uint4*)(gB + 8);
    uint4 rb2 = *(const uint4*)(gB + 16), rb3 = *(const uint4*)(gB + 24);

    floatx4 acc[4][4];
#pragma unroll
    for (int i = 0; i < 4; ++i)
#pragma unroll
        for (int j = 0; j < 4; ++j) acc[i][j] = (floatx4){0.f, 0.f, 0.f, 0.f};

    const int niter = K >> 6;
    for (int kb = 0; kb < niter; ++kb) {
        __syncthreads();
        *(uint4*)(lA + 0) = ra0;  *(uint4*)(lA + 8) = ra1;
        *(uint4*)(lA + 16) = ra2; *(uint4*)(lA + 24) = ra3;
        *(uint4*)(lB + 0) = rb0;  *(uint4*)(lB + 8) = rb1;
        *(uint4*)(lB + 16) = rb2; *(uint4*)(lB + 24) = rb3;
        __syncthreads();
        if (kb + 1 < niter) {
            const ushort_t* ga = gA + (size_t)(kb + 1) * 64;
            const ushort_t* gb = gB + (size_t)(kb + 1) * 64;
            ra0 = *(const uint4*)(ga + 0);  ra1 = *(const uint4*)(ga + 8);
            ra2 = *(const uint4*)(ga + 16); ra3 = *(const uint4*)(ga + 24);
            rb0 = *(const uint4*)(gb + 0);  rb1 = *(const uint4*)(gb + 8);
            rb2 = *(const uint4*)(gb + 16); rb3 = *(const uint4*)(gb + 24);
        }
        short8 av[4][2];
#pragma unroll
        for (int mt = 0; mt < 4; ++mt) {
            const int mr = wm * 64 + mt * 16 + l15;
            av[mt][0] = *(const short8*)(&At[mr * 72 + quad * 8]);
            av[mt][1] = *(const short8*)(&At[mr * 72 + 32 + quad * 8]);
        }
#pragma unroll
        for (int nt = 0; nt < 4; ++nt) {
            const int nr = wn * 64 + nt * 16 + l15;
            short8 b0 = *(const short8*)(&Bt[nr * 72 + quad * 8]);
            short8 b1 = *(const short8*)(&Bt[nr * 72 + 32 + quad * 8]);
#pragma unroll
            for (int mt = 0; mt < 4; ++mt) {
                acc[mt][nt] = __builtin_amdgcn_mfma_f32_16x16x32_bf16(av[mt][0], b0, acc[mt][nt], 0, 0, 0);
                acc[mt][nt] = __builtin_amdgcn_mfma_f32_16x16x32_bf16(av[mt][1], b1, acc[mt][nt], 0, 0, 0);
            }
        }
    }
#pragma unroll
    for (int mt = 0; mt < 4; ++mt)
#pragma unroll
        for (int nt = 0; nt < 4; ++nt) {
            const int col = n0 + wn * 64 + nt * 16 + l15;
            const float bb = bias[col];
#pragma unroll
            for (int r = 0; r < 4; ++r) {
                const int row = m0 + wm * 64 + mt * 16 + quad * 4 + r;
                const float v = acc[mt][nt][r] + bb;
                if (OUTF32) outf[(size_t)row * Nst + col] = v;
                else        outb[(size_t)row * Nst + col] = f2bf(v);
            }
        }
}

// ---------------------------------------------------------------------------
// LayerNorm + residual: z = h + relu( LN(hn)*g + b ), in-place over hbf.
// ---------------------------------------------------------------------------
__global__ __launch_bounds__(256, 1) void k_ln(const ushort_t* __restrict__ hn,
                                               ushort_t* __restrict__ h,
                                               const float* __restrict__ g,
                                               const float* __restrict__ bb) {
    const int tid = threadIdx.x;
    const int lane = tid & 63;
    const int row = blockIdx.x * 4 + (tid >> 6);
    const uint4 hv = *(const uint4*)(hn + (size_t)row * 512 + lane * 8);
    float f[8];
    f[0] = blo(hv.x); f[1] = bhi(hv.x); f[2] = blo(hv.y); f[3] = bhi(hv.y);
    f[4] = blo(hv.z); f[5] = bhi(hv.z); f[6] = blo(hv.w); f[7] = bhi(hv.w);
    float s = 0.f, s2 = 0.f;
#pragma unroll
    for (int j = 0; j < 8; ++j) { s += f[j]; s2 = fmaf(f[j], f[j], s2); }
#pragma unroll
    for (int o = 32; o >= 1; o >>= 1) { s += __shfl_xor(s, o, 64); s2 += __shfl_xor(s2, o, 64); }
    const float mu = s * (1.f / 512.f);
    const float var = s2 * (1.f / 512.f) - mu * mu;
    const float rs = rsqrtf(var + 1e-5f);
    const uint4 hh = *(const uint4*)(h + (size_t)row * 512 + lane * 8);
    float hf[8];
    hf[0] = blo(hh.x); hf[1] = bhi(hh.x); hf[2] = blo(hh.y); hf[3] = bhi(hh.y);
    hf[4] = blo(hh.z); hf[5] = bhi(hh.z); hf[6] = blo(hh.w); hf[7] = bhi(hh.w);
    float4 g0 = *(const float4*)(g + lane * 8);  float4 g1 = *(const float4*)(g + lane * 8 + 4);
    float4 b0 = *(const float4*)(bb + lane * 8); float4 b1 = *(const float4*)(bb + lane * 8 + 4);
    const float gv[8] = {g0.x, g0.y, g0.z, g0.w, g1.x, g1.y, g1.z, g1.w};
    const float bv[8] = {b0.x, b0.y, b0.z, b0.w, b1.x, b1.y, b1.z, b1.w};
    float z[8];
#pragma unroll
    for (int j = 0; j < 8; ++j)
        z[j] = hf[j] + fmaxf((f[j] - mu) * rs * gv[j] + bv[j], 0.f);
    uint4 o;
    o.x = pack2(z[0], z[1]); o.y = pack2(z[2], z[3]);
    o.z = pack2(z[4], z[5]); o.w = pack2(z[6], z[7]);
    *(uint4*)(h + (size_t)row * 512 + lane * 8) = o;
}

// ---------------------------------------------------------------------------
extern "C" void kernel_launch(void* const* d_in, const int* in_sizes, int n_in,
                              void* d_out, int out_size, void* d_ws, size_t ws_size,
                              hipStream_t stream) {
    const float* x    = (const float*)d_in[0];
    const float* Wcc  = (const float*)d_in[1];
    const float* bcc  = (const float*)d_in[2];
    const float* Wic  = (const float*)d_in[3];
    const float* bic  = (const float*)d_in[4];
    const float* Wmap = (const float*)d_in[5];
    const float* bmap = (const float*)d_in[6];
    const float* Whh  = (const float*)d_in[7];
    const float* bhh  = (const float*)d_in[8];
    const float* ln_g = (const float*)d_in[9];
    const float* ln_b = (const float*)d_in[10];
    const float* Who  = (const float*)d_in[11];
    const float* bho  = (const float*)d_in[12];
    float* out = (float*)d_out;

    char* wsb = (char*)d_ws;
    ushort_t* WbT  = (ushort_t*)(wsb);                    // 16,842,752 B + 1 KB pad
    ushort_t* Whhb = (ushort_t*)(wsb + 16843776);         //    524,288
    ushort_t* Whob = (ushort_t*)(wsb + 17368064);         //    131,072
    ushort_t* xbf  = (ushort_t*)(wsb + 17499136);         //  4,194,304
    float*    CTXT = (float*)   (wsb + 21693440);         // 33,554,432
    ushort_t* hbf  = (ushort_t*)(wsb + 55247872);         // 33,554,432 (h, then z)
    ushort_t* hnbf = (ushort_t*)(wsb + 88802304);         // 33,554,432 -> ~122 MB

    k_fused<<<1052, 256, 0, stream>>>(x, Wcc, bcc, Wic, bic, Wmap, bmap, Whh, Who,
                                      WbT, Whhb, Whob, xbf, CTXT, out + 4194304);
    k_big<<<1024, 512, 0, stream>>>(xbf, WbT, CTXT, hbf);
    k_gemm_nt<false><<<dim3(256, 4), 256, 0, stream>>>(hbf, Whhb, bhh, hnbf, nullptr, 512, 512);
    k_ln<<<8192, 256, 0, stream>>>(hnbf, hbf, ln_g, ln_b);
    k_gemm_nt<true><<<dim3(256, 1), 256, 0, stream>>>(hbf, Whob, bho, nullptr, out, 512, 128);
}

// Round 4
// 922.398 us; speedup vs baseline: 1.8758x; 1.0366x over previous
//
#include <hip/hip_runtime.h>

// ---------------------------------------------------------------------------
// InputMapCTRNN: T=256, B=128, I=64, C=256, H=512, O=128, ALPHA=1, EPS=1e-5
//
// h[t,b,n] = relu( sum_c ctx[t,b,c]*S_c + S_bias ),
//   S_c[m,n] = sum_i x[m,i]*WbT[n, c*64+i]  -> one MFMA GEMM M=32768,N=512,
//   K=16448. Scale folded into A: ahat[m, c*64+i] = bf16(ctx[m,c]*x[m,i])
//   built per-fragment in registers (scale is a per-lane scalar) -> pure
//   MFMA accumulation chain, LDS double-buffered glds staging of B.
// Recurrence: K=320 batched MFMA  ctx' = relu([Wcc|Wic] @ [ctx;x] + bias),
//   fused in one grid with the prep blocks (prep hides under recurrence).
// ---------------------------------------------------------------------------

typedef unsigned int  uint_t;
typedef unsigned short ushort_t;
typedef __attribute__((ext_vector_type(8))) short  short8;
typedef __attribute__((ext_vector_type(4))) short  short4v;
typedef __attribute__((ext_vector_type(4))) float  floatx4;

__device__ __forceinline__ ushort_t f2bf(float f) {
    uint_t u = __float_as_uint(f);
    u = (u + 0x7fffu + ((u >> 16) & 1u)) >> 16;   // RNE
    return (ushort_t)u;
}
__device__ __forceinline__ uint_t pack2(float a, float b) {
    return (uint_t)f2bf(a) | ((uint_t)f2bf(b) << 16);
}
__device__ __forceinline__ float blo(uint_t u) { return __uint_as_float(u << 16); }
__device__ __forceinline__ float bhi(uint_t u) { return __uint_as_float(u & 0xffff0000u); }

__device__ __forceinline__ void glds16(const void* g, void* l) {
    __builtin_amdgcn_global_load_lds(
        (const __attribute__((address_space(1))) unsigned int*)g,
        (__attribute__((address_space(3))) unsigned int*)l, 16, 0, 0);
}

// scale 8 packed bf16 by fp32 scalar, repack (round-half-up)
__device__ __forceinline__ short8 scale8(short8 a, float s) {
    union { short8 v; uint_t u[4]; } in, out;
    in.v = a;
#pragma unroll
    for (int q = 0; q < 4; ++q) {
        uint_t lo = __float_as_uint(blo(in.u[q]) * s);
        uint_t hi = __float_as_uint(bhi(in.u[q]) * s);
        out.u[q] = ((lo + 0x8000u) >> 16) | ((hi + 0x8000u) & 0xffff0000u);
    }
    return out.v;
}

// ---------------------------------------------------------------------------
// FUSED: blocks 0..7 = sequential ctx recurrence (K=320 MFMA, 1 barrier/step,
// LDS double-buffer, x read fp32 from input). blocks 8..1051 = prep (WbT
// transpose+cvt, Whh/Who/x -> bf16) — independent, hides under recurrence.
// ---------------------------------------------------------------------------
__global__ __launch_bounds__(256, 1) void k_fused(
        const float* __restrict__ x, const float* __restrict__ Wcc,
        const float* __restrict__ bcc, const float* __restrict__ Wic,
        const float* __restrict__ bic, const float* __restrict__ Wmap,
        const float* __restrict__ bmap, const float* __restrict__ Whh,
        const float* __restrict__ Who,
        ushort_t* WbT, ushort_t* Whhb, ushort_t* Whob, ushort_t* xbf,
        float* __restrict__ CTXT, float* __restrict__ ctx_out) {
    __shared__ __align__(16) char smem[32896];   // union: prep 32896 B / rec 20480 B
    const int tid = threadIdx.x;
    const int bid = blockIdx.x;

    if (bid >= 8) {
        const int pb = bid - 8;
        if (pb < 512) {                      // WbT[n][c*64+i] = Wmap[n*64+i][c]
            float* tl = (float*)smem;        // 32*257 floats
            const int n = pb;
            for (int p = 0; p < 2; ++p) {
                if (p) __syncthreads();
#pragma unroll
                for (int k = 0; k < 32; ++k)
                    tl[k * 257 + tid] = Wmap[(size_t)(n * 64 + p * 32 + k) * 256 + tid];
                __syncthreads();
#pragma unroll
                for (int k2 = 0; k2 < 32; ++k2) {
                    int o = k2 * 256 + tid;
                    int il = o & 31, c = o >> 5;
                    WbT[(size_t)n * 16448 + c * 64 + p * 32 + il] = f2bf(tl[il * 257 + c]);
                }
            }
            if (tid < 64) WbT[(size_t)n * 16448 + 16384 + tid] = f2bf(bmap[n * 64 + tid]);
        } else if (pb < 528) {
            size_t base = (size_t)(pb - 512) * 16384;
#pragma unroll
            for (int k = 0; k < 64; ++k) { size_t i = base + k * 256 + tid; Whhb[i] = f2bf(Whh[i]); }
        } else if (pb < 532) {
            size_t base = (size_t)(pb - 528) * 16384;
#pragma unroll
            for (int k = 0; k < 64; ++k) { size_t i = base + k * 256 + tid; Whob[i] = f2bf(Who[i]); }
        } else {
            size_t base = (size_t)(pb - 532) * 4096;
#pragma unroll
            for (int k = 0; k < 16; ++k) { size_t i = base + k * 256 + tid; xbf[i] = f2bf(x[i]); }
        }
        return;
    }

    // ---------------- recurrence: block g owns samples [g*16, g*16+16) ------
    char* bufs = smem;                          // 2 x 10240 B
    const int g = bid;
    const int lane = tid & 63, w = tid >> 6;
    const int l15 = lane & 15, quad = lane >> 4;
    const int bq = tid >> 4, o4 = tid & 15;     // x-staging role

    // A-fragments: Wcc (kb 0..7) + Wic (kb 8..9); row j = w*64+mt*16+l15
    short8 wf[4][8], wi[4][2];
#pragma unroll
    for (int mt = 0; mt < 4; ++mt) {
        const int j = w * 64 + mt * 16 + l15;
#pragma unroll
        for (int kb = 0; kb < 8; ++kb) {
            const float* src = Wcc + (size_t)j * 256 + kb * 32 + quad * 8;
            float4 a = *(const float4*)src;
            float4 b = *(const float4*)(src + 4);
            short8 s;
            s[0] = (short)f2bf(a.x); s[1] = (short)f2bf(a.y);
            s[2] = (short)f2bf(a.z); s[3] = (short)f2bf(a.w);
            s[4] = (short)f2bf(b.x); s[5] = (short)f2bf(b.y);
            s[6] = (short)f2bf(b.z); s[7] = (short)f2bf(b.w);
            wf[mt][kb] = s;
        }
#pragma unroll
        for (int kb = 0; kb < 2; ++kb) {
            const float* src = Wic + (size_t)j * 64 + kb * 32 + quad * 8;
            float4 a = *(const float4*)src;
            float4 b = *(const float4*)(src + 4);
            short8 s;
            s[0] = (short)f2bf(a.x); s[1] = (short)f2bf(a.y);
            s[2] = (short)f2bf(a.z); s[3] = (short)f2bf(a.w);
            s[4] = (short)f2bf(b.x); s[5] = (short)f2bf(b.y);
            s[6] = (short)f2bf(b.z); s[7] = (short)f2bf(b.w);
            wi[mt][kb] = s;
        }
    }
    float4 bias[4];
#pragma unroll
    for (int mt = 0; mt < 4; ++mt) {
        const int j0 = w * 64 + mt * 16 + quad * 4;
        float4 b1 = *(const float4*)(bic + j0);
        float4 b2 = *(const float4*)(bcc + j0);
        bias[mt] = (float4){b1.x + b2.x, b1.y + b2.y, b1.z + b2.z, b1.w + b2.w};
    }
    // init buf0: ctx=0 (granule rows 0..31), x_0 (rows 32..39)
    *(uint4*)(bufs + tid * 16) = (uint4){0, 0, 0, 0};
    *(uint4*)(bufs + (tid + 256) * 16) = (uint4){0, 0, 0, 0};
    {
        float4 xv = *(const float4*)(x + (size_t)(g * 16 + bq) * 64 + o4 * 4);
        short4v s4;
        s4[0] = (short)f2bf(xv.x); s4[1] = (short)f2bf(xv.y);
        s4[2] = (short)f2bf(xv.z); s4[3] = (short)f2bf(xv.w);
        *(short4v*)(bufs + (32 + (o4 >> 1)) * 256 + bq * 16 + (o4 & 1) * 8) = s4;
    }
    float4 y[4];
#pragma unroll
    for (int mt = 0; mt < 4; ++mt) y[mt] = (float4){0.f, 0.f, 0.f, 0.f};
    __syncthreads();

    int p = 0;
#pragma unroll 1
    for (int t = 0; t < 256; ++t) {
        char* bp = bufs + p * 10240;
        char* bn = bufs + (p ^ 1) * 10240;
        // CTXT[c][t*128 + b] = ctx entering step t (= y)
#pragma unroll
        for (int mt = 0; mt < 4; ++mt) {
            const int j0 = w * 64 + mt * 16 + quad * 4;
#pragma unroll
            for (int r = 0; r < 4; ++r)
                CTXT[(size_t)(j0 + r) * 32768 + t * 128 + g * 16 + l15] = (&y[mt].x)[r];
        }
        float4 xv;
        if (t < 255)
            xv = *(const float4*)(x + (size_t)((t + 1) * 128 + g * 16 + bq) * 64 + o4 * 4);
        floatx4 acc[4];
#pragma unroll
        for (int mt = 0; mt < 4; ++mt) acc[mt] = (floatx4){0.f, 0.f, 0.f, 0.f};
#pragma unroll
        for (int kb = 0; kb < 8; ++kb) {
            short8 bf = *(const short8*)(bp + (kb * 4 + quad) * 256 + l15 * 16);
#pragma unroll
            for (int mt = 0; mt < 4; ++mt)
                acc[mt] = __builtin_amdgcn_mfma_f32_16x16x32_bf16(wf[mt][kb], bf, acc[mt], 0, 0, 0);
        }
#pragma unroll
        for (int kb = 0; kb < 2; ++kb) {
            short8 bf = *(const short8*)(bp + ((8 + kb) * 4 + quad) * 256 + l15 * 16);
#pragma unroll
            for (int mt = 0; mt < 4; ++mt)
                acc[mt] = __builtin_amdgcn_mfma_f32_16x16x32_bf16(wi[mt][kb], bf, acc[mt], 0, 0, 0);
        }
#pragma unroll
        for (int mt = 0; mt < 4; ++mt) {
            y[mt].x = fmaxf(acc[mt][0] + bias[mt].x, 0.f);
            y[mt].y = fmaxf(acc[mt][1] + bias[mt].y, 0.f);
            y[mt].z = fmaxf(acc[mt][2] + bias[mt].z, 0.f);
            y[mt].w = fmaxf(acc[mt][3] + bias[mt].w, 0.f);
        }
        if (t < 255) {
#pragma unroll
            for (int mt = 0; mt < 4; ++mt) {
                const int c0 = w * 64 + mt * 16 + quad * 4;
                short4v s4;
                s4[0] = (short)f2bf(y[mt].x); s4[1] = (short)f2bf(y[mt].y);
                s4[2] = (short)f2bf(y[mt].z); s4[3] = (short)f2bf(y[mt].w);
                *(short4v*)(bn + (c0 >> 3) * 256 + l15 * 16 + (c0 & 7) * 2) = s4;
            }
            short4v s4;
            s4[0] = (short)f2bf(xv.x); s4[1] = (short)f2bf(xv.y);
            s4[2] = (short)f2bf(xv.z); s4[3] = (short)f2bf(xv.w);
            *(short4v*)(bn + (32 + (o4 >> 1)) * 256 + bq * 16 + (o4 & 1) * 8) = s4;
        }
        __syncthreads();
        p ^= 1;
    }
#pragma unroll
    for (int mt = 0; mt < 4; ++mt) {
        const int j0 = w * 64 + mt * 16 + quad * 4;
#pragma unroll
        for (int r = 0; r < 4; ++r)
            ctx_out[(size_t)(g * 16 + l15) * 256 + j0 + r] = (&y[mt].x)[r];
    }
}

// ---------------------------------------------------------------------------
// BIG GEMM: M=32768,N=512,K=16448, scale folded into A-fragments.
// 512 thr / 8 waves, block tile 128x128, wave tile 16m x 128n.
// BK=128, LDS DOUBLE-buffer (2x32 KB), glds(16B) for tile kk+1 issued right
// after the single per-iter barrier -> latency hidden behind compute.
// 1D grid 1024, XCD swizzle: by = gidx&3 (one WbT slice per XCD).
// ---------------------------------------------------------------------------
__global__ __launch_bounds__(512, 4) void k_big(const ushort_t* __restrict__ xbf,
                                                const ushort_t* __restrict__ WbT,
                                                const float* __restrict__ CTXT,
                                                ushort_t* __restrict__ hbf) {
    __shared__ __align__(16) ushort_t Bt[2 * 128 * 128];   // 64 KB
    const int tid = threadIdx.x;
    const int lane = tid & 63, w = tid >> 6;               // 8 waves
    const int l15 = lane & 15, quad = lane >> 4;
    const int gidx = blockIdx.x;
    const int by = gidx & 3;                               // xcd = gidx&7
    const int bx = (gidx >> 3) * 2 + ((gidx >> 2) & 1);
    const int m0 = bx * 128, n0 = by * 128;
    const int mrow = m0 + w * 16 + l15;                    // this lane's A-row

    short8 afr[2];                                         // x row frag, k=ks*32+quad*8
    afr[0] = *(const short8*)(xbf + (size_t)mrow * 64 + quad * 8);
    afr[1] = *(const short8*)(xbf + (size_t)mrow * 64 + 32 + quad * 8);

    floatx4 acc[8];
#pragma unroll
    for (int nt = 0; nt < 8; ++nt) acc[nt] = (floatx4){0.f, 0.f, 0.f, 0.f};

    // staging: granule G = w*256 + q*64 + lane; nr=G>>4; k8=(G&15)^(nr&15)
    const ushort_t* gq[4];
    ushort_t* lq[4];
#pragma unroll
    for (int q = 0; q < 4; ++q) {
        const int G = w * 256 + q * 64 + lane;
        const int nr = G >> 4;
        const int k8 = (G & 15) ^ (nr & 15);
        gq[q] = WbT + (size_t)(n0 + nr) * 16448 + k8 * 8;
        lq[q] = Bt + w * 2048 + q * 512;                   // wave-uniform base
    }
#pragma unroll
    for (int q = 0; q < 4; ++q) glds16(gq[q], lq[q]);      // tile 0 -> buf 0

    float scv0 = CTXT[mrow];
    float scv1 = CTXT[32768 + mrow];

    for (int kk = 0; kk < 129; ++kk) {
        const int p = kk & 1;
        __syncthreads();                                   // tile kk resident
        if (kk < 128) {                                    // prefetch tile kk+1
            const size_t koff = (size_t)(kk + 1) * 128;
            const int np = (p ^ 1) * 16384;
#pragma unroll
            for (int q = 0; q < 4; ++q) glds16(gq[q] + koff, lq[q] + np);
        }
        float scn0 = 1.f, scn1 = 1.f;
        if (kk + 1 < 128) {
            scn0 = CTXT[(size_t)(2 * kk + 2) * 32768 + mrow];
            scn1 = CTXT[(size_t)(2 * kk + 3) * 32768 + mrow];
        }
        const ushort_t* bb = Bt + p * 16384;
        if (kk < 128) {
#pragma unroll
            for (int h = 0; h < 2; ++h) {
                const float s = h ? scv1 : scv0;
                short8 ah0 = scale8(afr[0], s);
                short8 ah1 = scale8(afr[1], s);
#pragma unroll
                for (int nt = 0; nt < 8; ++nt) {
                    const int nr = nt * 16 + l15;
                    const char* bpr = (const char*)bb + nr * 256;
                    short8 b0 = *(const short8*)(bpr + (((h * 8 + quad) ^ l15) * 16));
                    short8 b1 = *(const short8*)(bpr + (((h * 8 + 4 + quad) ^ l15) * 16));
                    acc[nt] = __builtin_amdgcn_mfma_f32_16x16x32_bf16(ah0, b0, acc[nt], 0, 0, 0);
                    acc[nt] = __builtin_amdgcn_mfma_f32_16x16x32_bf16(ah1, b1, acc[nt], 0, 0, 0);
                }
            }
        } else {                                           // bias block, scale=1
#pragma unroll
            for (int nt = 0; nt < 8; ++nt) {
                const int nr = nt * 16 + l15;
                const char* bpr = (const char*)bb + nr * 256;
                short8 b0 = *(const short8*)(bpr + ((quad ^ l15) * 16));
                short8 b1 = *(const short8*)(bpr + (((4 + quad) ^ l15) * 16));
                acc[nt] = __builtin_amdgcn_mfma_f32_16x16x32_bf16(afr[0], b0, acc[nt], 0, 0, 0);
                acc[nt] = __builtin_amdgcn_mfma_f32_16x16x32_bf16(afr[1], b1, acc[nt], 0, 0, 0);
            }
        }
        scv0 = scn0; scv1 = scn1;
    }
    // epilogue: C/D col = n0+nt*16+l15, row = m0 + w*16 + quad*4 + r
#pragma unroll
    for (int nt = 0; nt < 8; ++nt) {
        const int col = n0 + nt * 16 + l15;
#pragma unroll
        for (int r = 0; r < 4; ++r) {
            const int row = m0 + w * 16 + quad * 4 + r;
            hbf[(size_t)row * 512 + col] = f2bf(fmaxf(acc[nt][r], 0.f));
        }
    }
}

// ---------------------------------------------------------------------------
// Generic bf16 NT GEMM: C[m,n] = sum_k A[m,k]*B[n,k] + bias[n]
// ---------------------------------------------------------------------------
template <bool OUTF32>
__global__ __launch_bounds__(256, 2) void k_gemm_nt(const ushort_t* __restrict__ A,
                                                    const ushort_t* __restrict__ Bm,
                                                    const float* __restrict__ bias,
                                                    ushort_t* __restrict__ outb,
                                                    float* __restrict__ outf,
                                                    int K, int Nst) {
    __shared__ __align__(16) ushort_t At[128 * 72];
    __shared__ __align__(16) ushort_t Bt[128 * 72];
    const int tid = threadIdx.x;
    const int lane = tid & 63, w = tid >> 6;
    const int wm = w & 1, wn = w >> 1;
    const int l15 = lane & 15, quad = lane >> 4;
    const int m0 = blockIdx.x * 128, n0 = blockIdx.y * 128;

    const int r_l = tid >> 1, kh = (tid & 1) * 32;
    const ushort_t* gA = A + (size_t)(m0 + r_l) * K + kh;
    const ushort_t* gB = Bm + (size_t)(n0 + r_l) * K + kh;
    ushort_t* lA = &At[r_l * 72 + kh];
    ushort_t* lB = &Bt[r_l * 72 + kh];

    uint4 ra0 = *(const uint4*)(gA + 0), ra1 = *(const uint4*)(gA + 8);
    uint4 ra2 = *(const uint4*)(gA + 16), ra3 = *(const uint4*)(gA + 24);
    uint4 rb0 = *(const uint4*)(gB + 0), rb1 = *(const uint4*)(gB + 8);
    uint4 rb2 = *(const uint4*)(gB + 16), rb3 = *(const uint4*)(gB + 24);

    floatx4 acc[4][4];
#pragma unroll
    for (int i = 0; i < 4; ++i)
#pragma unroll
        for (int j = 0; j < 4; ++j) acc[i][j] = (floatx4){0.f, 0.f, 0.f, 0.f};

    const int niter = K >> 6;
    for (int kb = 0; kb < niter; ++kb) {
        __syncthreads();
        *(uint4*)(lA + 0) = ra0;  *(uint4*)(lA + 8) = ra1;
        *(uint4*)(lA + 16) = ra2; *(uint4*)(lA + 24) = ra3;
        *(uint4*)(lB + 0) = rb0;  *(uint4*)(lB + 8) = rb1;
        *(uint4*)(lB + 16) = rb2; *(uint4*)(lB + 24) = rb3;
        __syncthreads();
        if (kb + 1 < niter) {
            const ushort_t* ga = gA + (size_t)(kb + 1) * 64;
            const ushort_t* gb = gB + (size_t)(kb + 1) * 64;
            ra0 = *(const uint4*)(ga + 0);  ra1 = *(const uint4*)(ga + 8);
            ra2 = *(const uint4*)(ga + 16); ra3 = *(const uint4*)(ga + 24);
            rb0 = *(const uint4*)(gb + 0);  rb1 = *(const uint4*)(gb + 8);
            rb2 = *(const uint4*)(gb + 16); rb3 = *(const uint4*)(gb + 24);
        }
        short8 av[4][2];
#pragma unroll
        for (int mt = 0; mt < 4; ++mt) {
            const int mr = wm * 64 + mt * 16 + l15;
            av[mt][0] = *(const short8*)(&At[mr * 72 + quad * 8]);
            av[mt][1] = *(const short8*)(&At[mr * 72 + 32 + quad * 8]);
        }
#pragma unroll
        for (int nt = 0; nt < 4; ++nt) {
            const int nr = wn * 64 + nt * 16 + l15;
            short8 b0 = *(const short8*)(&Bt[nr * 72 + quad * 8]);
            short8 b1 = *(const short8*)(&Bt[nr * 72 + 32 + quad * 8]);
#pragma unroll
            for (int mt = 0; mt < 4; ++mt) {
                acc[mt][nt] = __builtin_amdgcn_mfma_f32_16x16x32_bf16(av[mt][0], b0, acc[mt][nt], 0, 0, 0);
                acc[mt][nt] = __builtin_amdgcn_mfma_f32_16x16x32_bf16(av[mt][1], b1, acc[mt][nt], 0, 0, 0);
            }
        }
    }
#pragma unroll
    for (int mt = 0; mt < 4; ++mt)
#pragma unroll
        for (int nt = 0; nt < 4; ++nt) {
            const int col = n0 + wn * 64 + nt * 16 + l15;
            const float bb = bias[col];
#pragma unroll
            for (int r = 0; r < 4; ++r) {
                const int row = m0 + wm * 64 + mt * 16 + quad * 4 + r;
                const float v = acc[mt][nt][r] + bb;
                if (OUTF32) outf[(size_t)row * Nst + col] = v;
                else        outb[(size_t)row * Nst + col] = f2bf(v);
            }
        }
}

// ---------------------------------------------------------------------------
// LayerNorm + residual: z = h + relu( LN(hn)*g + b ), in-place over hbf.
// ---------------------------------------------------------------------------
__global__ __launch_bounds__(256, 1) void k_ln(const ushort_t* __restrict__ hn,
                                               ushort_t* __restrict__ h,
                                               const float* __restrict__ g,
                                               const float* __restrict__ bb) {
    const int tid = threadIdx.x;
    const int lane = tid & 63;
    const int row = blockIdx.x * 4 + (tid >> 6);
    const uint4 hv = *(const uint4*)(hn + (size_t)row * 512 + lane * 8);
    float f[8];
    f[0] = blo(hv.x); f[1] = bhi(hv.x); f[2] = blo(hv.y); f[3] = bhi(hv.y);
    f[4] = blo(hv.z); f[5] = bhi(hv.z); f[6] = blo(hv.w); f[7] = bhi(hv.w);
    float s = 0.f, s2 = 0.f;
#pragma unroll
    for (int j = 0; j < 8; ++j) { s += f[j]; s2 = fmaf(f[j], f[j], s2); }
#pragma unroll
    for (int o = 32; o >= 1; o >>= 1) { s += __shfl_xor(s, o, 64); s2 += __shfl_xor(s2, o, 64); }
    const float mu = s * (1.f / 512.f);
    const float var = s2 * (1.f / 512.f) - mu * mu;
    const float rs = rsqrtf(var + 1e-5f);
    const uint4 hh = *(const uint4*)(h + (size_t)row * 512 + lane * 8);
    float hf[8];
    hf[0] = blo(hh.x); hf[1] = bhi(hh.x); hf[2] = blo(hh.y); hf[3] = bhi(hh.y);
    hf[4] = blo(hh.z); hf[5] = bhi(hh.z); hf[6] = blo(hh.w); hf[7] = bhi(hh.w);
    float4 g0 = *(const float4*)(g + lane * 8);  float4 g1 = *(const float4*)(g + lane * 8 + 4);
    float4 b0 = *(const float4*)(bb + lane * 8); float4 b1 = *(const float4*)(bb + lane * 8 + 4);
    const float gv[8] = {g0.x, g0.y, g0.z, g0.w, g1.x, g1.y, g1.z, g1.w};
    const float bv[8] = {b0.x, b0.y, b0.z, b0.w, b1.x, b1.y, b1.z, b1.w};
    float z[8];
#pragma unroll
    for (int j = 0; j < 8; ++j)
        z[j] = hf[j] + fmaxf((f[j] - mu) * rs * gv[j] + bv[j], 0.f);
    uint4 o;
    o.x = pack2(z[0], z[1]); o.y = pack2(z[2], z[3]);
    o.z = pack2(z[4], z[5]); o.w = pack2(z[6], z[7]);
    *(uint4*)(h + (size_t)row * 512 + lane * 8) = o;
}

// ---------------------------------------------------------------------------
extern "C" void kernel_launch(void* const* d_in, const int* in_sizes, int n_in,
                              void* d_out, int out_size, void* d_ws, size_t ws_size,
                              hipStream_t stream) {
    const float* x    = (const float*)d_in[0];
    const float* Wcc  = (const float*)d_in[1];
    const float* bcc  = (const float*)d_in[2];
    const float* Wic  = (const float*)d_in[3];
    const float* bic  = (const float*)d_in[4];
    const float* Wmap = (const float*)d_in[5];
    const float* bmap = (const float*)d_in[6];
    const float* Whh  = (const float*)d_in[7];
    const float* bhh  = (const float*)d_in[8];
    const float* ln_g = (const float*)d_in[9];
    const float* ln_b = (const float*)d_in[10];
    const float* Who  = (const float*)d_in[11];
    const float* bho  = (const float*)d_in[12];
    float* out = (float*)d_out;

    char* wsb = (char*)d_ws;
    ushort_t* WbT  = (ushort_t*)(wsb);                    // 16,842,752 B + 1 KB pad
    ushort_t* Whhb = (ushort_t*)(wsb + 16843776);         //    524,288
    ushort_t* Whob = (ushort_t*)(wsb + 17368064);         //    131,072
    ushort_t* xbf  = (ushort_t*)(wsb + 17499136);         //  4,194,304
    float*    CTXT = (float*)   (wsb + 21693440);         // 33,554,432
    ushort_t* hbf  = (ushort_t*)(wsb + 55247872);         // 33,554,432 (h, then z)
    ushort_t* hnbf = (ushort_t*)(wsb + 88802304);         // 33,554,432 -> ~122 MB

    k_fused<<<1052, 256, 0, stream>>>(x, Wcc, bcc, Wic, bic, Wmap, bmap, Whh, Who,
                                      WbT, Whhb, Whob, xbf, CTXT, out + 4194304);
    k_big<<<1024, 512, 0, stream>>>(xbf, WbT, CTXT, hbf);
    k_gemm_nt<false><<<dim3(256, 4), 256, 0, stream>>>(hbf, Whhb, bhh, hnbf, nullptr, 512, 512);
    k_ln<<<8192, 256, 0, stream>>>(hnbf, hbf, ln_g, ln_b);
    k_gemm_nt<true><<<dim3(256, 1), 256, 0, stream>>>(hbf, Whob, bho, nullptr, out, 512, 128);
}